// Round 8
// baseline (4271.129 us; speedup 1.0000x reference)
//
#include <hip/hip_runtime.h>
#include <hip/hip_bf16.h>

#define T_STEPS 512
#define BATCH 64
#define TB (T_STEPS * BATCH)   // 32768

typedef short bf16x8 __attribute__((ext_vector_type(8)));
typedef float f32x4 __attribute__((ext_vector_type(4)));

union FragU { uint4 u; bf16x8 v; };

static __device__ __forceinline__ bf16x8 ld_frag(const uint4* p) {
  FragU f; f.u = *p; return f.v;
}

static __device__ __forceinline__ unsigned short f2bf(float f) {
  unsigned u = __float_as_uint(f);
  return (unsigned short)((u + 0x7FFFu + ((u >> 16) & 1u)) >> 16);
}

static __device__ __forceinline__ int revrow(int r) {
  int t = r >> 6, b = r & 63;
  return ((T_STEPS - 1 - t) << 6) | b;
}

#define S_RZ  (-1.4426950408889634f)   /* -log2(e)   : sigmoid(p)=1/(1+2^(S_RZ*p)) */
#define S_C   (-2.8853900817779268f)   /* -2*log2(e) : tanh(p)=2/(1+2^(S_C*p))-1   */

// ---- explicit named-AGPR weight residency -------------------------------------------
// Weights written ONCE to physical a0..a127; MFMAs reference a[N:N+3] literally.
// The register allocator cannot spill registers it does not manage.
#define AWR(N, x) asm volatile("v_accvgpr_write_b32 a" #N ", %0" :: "v"(x) : "a" #N)
#define LOADF(F, A0, A1, A2, A3) do { \
    uint4 t = whrzp[(size_t)(w * 32 + F) * 64 + lane]; \
    AWR(A0, t.x); AWR(A1, t.y); AWR(A2, t.z); AWR(A3, t.w); } while (0)

// MFMA with B from pinned AGPR range (literal) — D/C/A in arch VGPRs ("v").
#define MFMA_A(acc, va, B0, B3) \
  asm volatile("v_mfma_f32_16x16x32_bf16 %0, %1, a[" #B0 ":" #B3 "], %0" \
               : "+v"(acc) : "v"(va))
#define MFMA_A1(acc, va, B0, B3) \
  asm volatile("s_nop 1\n\tv_mfma_f32_16x16x32_bf16 %0, %1, a[" #B0 ":" #B3 "], %0" \
               : "+v"(acc) : "v"(va))
// MFMA with B from VGPR (LDS-read Whc)
#define MFMA_V(acc, va, vb) \
  asm volatile("v_mfma_f32_16x16x32_bf16 %0, %1, %2, %0" \
               : "+v"(acc) : "v"(va), "v"(vb))
#define MFMA_V1(acc, va, vb) \
  asm volatile("s_nop 1\n\tv_mfma_f32_16x16x32_bf16 %0, %1, %2, %0" \
               : "+v"(acc) : "v"(va), "v"(vb))
// fence before VALU reads of MFMA results (round-7-validated discipline)
#define ACCFENCE(acc) asm volatile("s_nop 7\n\ts_nop 7" : "+v"(acc))

#define ACLB \
  "a0","a1","a2","a3","a4","a5","a6","a7","a8","a9","a10","a11","a12","a13","a14","a15", \
  "a16","a17","a18","a19","a20","a21","a22","a23","a24","a25","a26","a27","a28","a29","a30","a31", \
  "a32","a33","a34","a35","a36","a37","a38","a39","a40","a41","a42","a43","a44","a45","a46","a47", \
  "a48","a49","a50","a51","a52","a53","a54","a55","a56","a57","a58","a59","a60","a61","a62","a63", \
  "a64","a65","a66","a67","a68","a69","a70","a71","a72","a73","a74","a75","a76","a77","a78","a79", \
  "a80","a81","a82","a83","a84","a85","a86","a87","a88","a89","a90","a91","a92","a93","a94","a95", \
  "a96","a97","a98","a99","a100","a101","a102","a103","a104","a105","a106","a107","a108","a109","a110","a111", \
  "a112","a113","a114","a115","a116","a117","a118","a119","a120","a121","a122","a123","a124","a125","a126","a127"

// ---------------- pack weights into MFMA B-fragment layout (with gate pre-scaling) ----
__global__ void pack_w_kernel(const float* __restrict__ W, int rows, int k_base,
                              int n_tiles, int k_tiles, int mode,
                              unsigned short* __restrict__ dst) {
  int gid = blockIdx.x * blockDim.x + threadIdx.x;
  int total = n_tiles * k_tiles * 64;
  if (gid >= total) return;
  int lane = gid & 63;
  int fi = gid >> 6;
  int kt = fi % k_tiles;
  int nt = fi / k_tiles;
  int n = nt * 16 + (lane & 15);
  int g, col; float s;
  if (mode == 0)      { g = n >> 8;            col = n & 255; s = (g == 1) ? S_C : S_RZ; }
  else if (mode == 1) { g = (n < 256) ? 0 : 2; col = n & 255; s = S_RZ; }
  else                { g = 1;                 col = n;       s = S_C; }
  int k0 = k_base + kt * 32 + ((lane >> 4) << 3);
  const float* src = W + ((size_t)g * rows + k0) * 256 + col;
  unsigned short v[8];
#pragma unroll
  for (int j = 0; j < 8; ++j) v[j] = f2bf(src[(size_t)j * 256] * s);
  uint4 o;
  o.x = v[0] | ((unsigned)v[1] << 16);
  o.y = v[2] | ((unsigned)v[3] << 16);
  o.z = v[4] | ((unsigned)v[5] << 16);
  o.w = v[6] | ((unsigned)v[7] << 16);
  ((uint4*)dst)[gid] = o;
}

static __device__ __forceinline__ bf16x8 cvt8(float4 f0, float4 f1) {
  uint4 o;
  o.x = f2bf(f0.x) | ((unsigned)f2bf(f0.y) << 16);
  o.y = f2bf(f0.z) | ((unsigned)f2bf(f0.w) << 16);
  o.z = f2bf(f1.x) | ((unsigned)f2bf(f1.y) << 16);
  o.w = f2bf(f1.z) | ((unsigned)f2bf(f1.w) << 16);
  FragU f; f.u = o; return f.v;
}

// ---------------- Xg GEMM (chunked): writes C-fragment tile layout --------------------
template<int LAYER>
__global__ __launch_bounds__(256)
void gemm_xg_kernel(const float* __restrict__ x,
                    const unsigned short* __restrict__ fs0,
                    const unsigned short* __restrict__ bs0,
                    const unsigned short* __restrict__ Bp,
                    const float* __restrict__ bias_fw,
                    const float* __restrict__ bias_bw,
                    f32x4* __restrict__ Xg, int t0, int chunkT)
{
  constexpr int KT = (LAYER == 0) ? 8 : 16;
  int dir = blockIdx.z;
  int lane = threadIdx.x & 63;
  int w = threadIdx.x >> 6;
  int ww = w >> 1, wc = w & 1;
  int mt0 = blockIdx.x * 8 + ww * 4;
  int nt0 = blockIdx.y * 8 + wc * 4;
  const uint4* B = (const uint4*)Bp + (size_t)dir * 48 * KT * 64;
  const int arow = lane & 15;
  const int k0b = ((lane >> 4) << 3);

  f32x4 acc[4][4] = {};
#pragma unroll
  for (int kt = 0; kt < KT; ++kt) {
    int k0 = kt * 32 + k0b;
    bf16x8 a[4], b[4];
#pragma unroll
    for (int i = 0; i < 4; ++i) {
      int grow = t0 * 64 + (mt0 + i) * 16 + arow;
      if (LAYER == 0) {
        int gr = dir ? revrow(grow) : grow;
        const float4* s = (const float4*)(x + (size_t)gr * 256 + k0);
        a[i] = cvt8(s[0], s[1]);
      } else {
        const unsigned short* base; int r2 = grow, kk = k0;
        if (k0 < 256) { base = dir ? bs0 : fs0; }
        else          { base = dir ? fs0 : bs0; r2 = revrow(grow); kk = k0 - 256; }
        a[i] = *(const bf16x8*)(base + (size_t)r2 * 256 + kk);
      }
    }
#pragma unroll
    for (int j = 0; j < 4; ++j) b[j] = ld_frag(B + ((size_t)(nt0 + j) * KT + kt) * 64 + lane);
#pragma unroll
    for (int i = 0; i < 4; ++i)
#pragma unroll
      for (int j = 0; j < 4; ++j)
        acc[i][j] = __builtin_amdgcn_mfma_f32_16x16x32_bf16(a[i], b[j], acc[i][j], 0, 0, 0);
  }

  const float* bias = dir ? bias_bw : bias_fw;
  f32x4* C = Xg + (size_t)dir * (chunkT * 4) * 48 * 64;
#pragma unroll
  for (int j = 0; j < 4; ++j) {
    int ct = nt0 + j;
    int col = ct * 16 + (lane & 15);
    int g = col >> 8, cc = col & 255;
    float bv = ((g == 1) ? S_C : S_RZ) * bias[g * 256 + cc];
#pragma unroll
    for (int i = 0; i < 4; ++i) {
      int rt = blockIdx.x * 8 + ww * 4 + i;
      f32x4 v = acc[i][j];
      v[0] += bv; v[1] += bv; v[2] += bv; v[3] += bv;
      C[((size_t)rt * 48 + ct) * 64 + lane] = v;
    }
  }
}

// ---------------- persistent recurrent GRU kernel (one layer, both dirs, chunked) -----
// grid (4, 2), 512 threads = 8 waves. Whrz: physical a0..a127 per wave (explicit AGPR).
// Whc: 128 KB LDS. fp32 h: 8 regs/wave.
template<int LAYER>
__global__ __launch_bounds__(512) __attribute__((amdgpu_waves_per_eu(2, 2)))
void gru_kernel(const f32x4* __restrict__ Xg,
                const uint4* __restrict__ whrz_fw, const uint4* __restrict__ whrz_bw, // [32][8][64]
                const uint4* __restrict__ whc_fw,  const uint4* __restrict__ whc_bw,  // [16][8][64]
                unsigned short* __restrict__ sfw_bf, unsigned short* __restrict__ sbw_bf,
                float* __restrict__ out,
                float* __restrict__ hstate, float* __restrict__ dout_h,
                int t0, int chunkT)
{
  const int dir = blockIdx.y;
  const int bx = blockIdx.x;
  const int row0 = bx * 16;
  const int tid = threadIdx.x;
  const int lane = tid & 63;
  const int w = tid >> 6;               // 0..7

  __shared__ __align__(16) unsigned short h_bf[16 * 256];   // swizzled bf16 h       (8 KB)
  __shared__ __align__(16) unsigned short rh_bf[16 * 256];  // swizzled bf16 r*h     (8 KB)
  __shared__ __align__(16) unsigned short z_h[16 * 256];    // fp16 z gate           (8 KB)
  __shared__ __align__(16) uint4 wc_lds[16 * 8 * 64];       // Whc B-fragments     (128 KB)

  const uint4* whrzp = dir ? whrz_bw : whrz_fw;
  const uint4* whcp  = dir ? whc_bw  : whc_fw;

  // stage Whc into LDS
  for (int i = tid; i < 16 * 8 * 64; i += 512) wc_lds[i] = whcp[i];

  // pin Whrz fragments into physical a0..a127 (frag F = ntile(w*4+F/8), kt=F%8)
  LOADF(0, 0, 1, 2, 3);     LOADF(1, 4, 5, 6, 7);     LOADF(2, 8, 9, 10, 11);   LOADF(3, 12, 13, 14, 15);
  LOADF(4, 16, 17, 18, 19); LOADF(5, 20, 21, 22, 23); LOADF(6, 24, 25, 26, 27); LOADF(7, 28, 29, 30, 31);
  LOADF(8, 32, 33, 34, 35); LOADF(9, 36, 37, 38, 39); LOADF(10, 40, 41, 42, 43); LOADF(11, 44, 45, 46, 47);
  LOADF(12, 48, 49, 50, 51); LOADF(13, 52, 53, 54, 55); LOADF(14, 56, 57, 58, 59); LOADF(15, 60, 61, 62, 63);
  LOADF(16, 64, 65, 66, 67); LOADF(17, 68, 69, 70, 71); LOADF(18, 72, 73, 74, 75); LOADF(19, 76, 77, 78, 79);
  LOADF(20, 80, 81, 82, 83); LOADF(21, 84, 85, 86, 87); LOADF(22, 88, 89, 90, 91); LOADF(23, 92, 93, 94, 95);
  LOADF(24, 96, 97, 98, 99); LOADF(25, 100, 101, 102, 103); LOADF(26, 104, 105, 106, 107); LOADF(27, 108, 109, 110, 111);
  LOADF(28, 112, 113, 114, 115); LOADF(29, 116, 117, 118, 119); LOADF(30, 120, 121, 122, 123); LOADF(31, 124, 125, 126, 127);

  const int ccol = lane & 15;
  const int crow = ((lane >> 4) << 2);     // 0,4,8,12

  float* hst = hstate + (size_t)(dir * 4 + bx) * 4096;
  for (int i = tid; i < 16 * 256; i += 512) {
    float v = (t0 == 0) ? 0.0f : hst[i];
    int rr = i >> 8, cc = i & 255;
    int cb = cc * 2;
    int byt = rr * 512 + (((cb & ~15) ^ ((rr & 7) << 4)) | (cb & 15));
    *(unsigned short*)((char*)h_bf + byt) = f2bf(v);
  }
  float hreg[2][4];
#pragma unroll
  for (int j = 0; j < 2; ++j)
#pragma unroll
    for (int r = 0; r < 4; ++r) {
      int rr = crow + r, c = (w * 2 + j) * 16 + ccol;
      hreg[j][r] = (t0 == 0) ? 0.0f : hst[rr * 256 + c];
    }
  __syncthreads();

  const int q0 = w * 4;                    // rz ntile base
  const bool is_r = (w < 4);
  const int ctA0 = is_r ? q0 : q0 + 16;    // Xg ct for rz ([r|cand|z] col order)
  const int ctB0 = 16 + w * 2;             // Xg ct for cand
  const f32x4* XgD = Xg + (size_t)dir * (chunkT * 4) * 48 * 64;
  unsigned short* sp_bf = dir ? sbw_bf : sfw_bf;
  const int coff = dir ? 256 : 0;
  const int ardbase = (lane & 15) * 512;
  const int arxor = ((lane & 7) << 4);
  const int afc = ((lane >> 4) << 4);

#define AFRAG(KT) (*(const bf16x8*)((const char*)h_bf + (ardbase + ((KT * 64 + afc) ^ arxor))))
#define RFRAG(KT) (*(const bf16x8*)((const char*)rh_bf + (ardbase + ((KT * 64 + afc) ^ arxor))))

#pragma unroll 1
  for (int t = t0; t < t0 + chunkT; ++t) {
    const int tloc = t - t0;
    const size_t rtb = ((size_t)(tloc * 4 + bx) * 48) * 64 + lane;
    f32x4 xa0 = XgD[rtb + (size_t)(ctA0 + 0) * 64];
    f32x4 xa1 = XgD[rtb + (size_t)(ctA0 + 1) * 64];
    f32x4 xa2 = XgD[rtb + (size_t)(ctA0 + 2) * 64];
    f32x4 xa3 = XgD[rtb + (size_t)(ctA0 + 3) * 64];

    // ---------- phase A: rz = h @ Whrz (+x-part), weights from pinned AGPRs ----------
    f32x4 accA0 = {}, accA1 = {}, accA2 = {}, accA3 = {};
    {
      bf16x8 af;
      af = AFRAG(0);
      MFMA_A1(accA0, af, 0, 3);   MFMA_A1(accA1, af, 32, 35);
      MFMA_A1(accA2, af, 64, 67); MFMA_A1(accA3, af, 96, 99);
      af = AFRAG(1);
      MFMA_A(accA0, af, 4, 7);    MFMA_A(accA1, af, 36, 39);
      MFMA_A(accA2, af, 68, 71);  MFMA_A(accA3, af, 100, 103);
      af = AFRAG(2);
      MFMA_A(accA0, af, 8, 11);   MFMA_A(accA1, af, 40, 43);
      MFMA_A(accA2, af, 72, 75);  MFMA_A(accA3, af, 104, 107);
      af = AFRAG(3);
      MFMA_A(accA0, af, 12, 15);  MFMA_A(accA1, af, 44, 47);
      MFMA_A(accA2, af, 76, 79);  MFMA_A(accA3, af, 108, 111);
      af = AFRAG(4);
      MFMA_A(accA0, af, 16, 19);  MFMA_A(accA1, af, 48, 51);
      MFMA_A(accA2, af, 80, 83);  MFMA_A(accA3, af, 112, 115);
      af = AFRAG(5);
      MFMA_A(accA0, af, 20, 23);  MFMA_A(accA1, af, 52, 55);
      MFMA_A(accA2, af, 84, 87);  MFMA_A(accA3, af, 116, 119);
      af = AFRAG(6);
      MFMA_A(accA0, af, 24, 27);  MFMA_A(accA1, af, 56, 59);
      MFMA_A(accA2, af, 88, 91);  MFMA_A(accA3, af, 120, 123);
      af = AFRAG(7);
      MFMA_A(accA0, af, 28, 31);  MFMA_A(accA1, af, 60, 63);
      MFMA_A(accA2, af, 92, 95);  MFMA_A(accA3, af, 124, 127);
    }
    // issue phase-B Xg loads early (land during epilogue A + phase B MFMAs)
    f32x4 xb0 = XgD[rtb + (size_t)(ctB0 + 0) * 64];
    f32x4 xb1 = XgD[rtb + (size_t)(ctB0 + 1) * 64];

    ACCFENCE(accA0); ACCFENCE(accA1); ACCFENCE(accA2); ACCFENCE(accA3);
#pragma unroll
    for (int j = 0; j < 4; ++j) {
      f32x4 ac = (j == 0) ? accA0 : (j == 1) ? accA1 : (j == 2) ? accA2 : accA3;
      f32x4 xv = (j == 0) ? xa0 : (j == 1) ? xa1 : (j == 2) ? xa2 : xa3;
      int cl = (q0 + j) * 16 + ccol;       // rz col 0..511
#pragma unroll
      for (int r = 0; r < 4; ++r) {
        int rr = crow + r;
        float v = ac[r] + xv[r];
        float gate = __builtin_amdgcn_rcpf(1.0f + __builtin_amdgcn_exp2f(v)); // sigmoid
        if (is_r) {
          int cb = cl * 2;
          int byt = rr * 512 + (((cb & ~15) ^ ((rr & 7) << 4)) | (cb & 15));
          unsigned short hu = *(const unsigned short*)((const char*)h_bf + byt);
          float h = __uint_as_float((unsigned)hu << 16);
          *(unsigned short*)((char*)rh_bf + byt) = f2bf(gate * h);
        } else {
          _Float16 zh = (_Float16)gate;
          z_h[rr * 256 + (cl - 256)] = __builtin_bit_cast(unsigned short, zh);
        }
      }
    }
    asm volatile("s_waitcnt lgkmcnt(0)" ::: "memory", ACLB);
    __builtin_amdgcn_s_barrier();

    // ---------- phase B: cand = tanh-form((r*h) @ Whc + x-part), update h ----------
    f32x4 accB0 = {}, accB1 = {};
#pragma unroll
    for (int kt = 0; kt < 8; ++kt) {
      bf16x8 a = RFRAG(kt);
      bf16x8 b0 = *(const bf16x8*)&wc_lds[((size_t)(w * 2 + 0) * 8 + kt) * 64 + lane];
      bf16x8 b1 = *(const bf16x8*)&wc_lds[((size_t)(w * 2 + 1) * 8 + kt) * 64 + lane];
      if (kt == 0) { MFMA_V1(accB0, a, b0); MFMA_V1(accB1, a, b1); }
      else         { MFMA_V(accB0, a, b0);  MFMA_V(accB1, a, b1); }
    }
    ACCFENCE(accB0); ACCFENCE(accB1);
    int gbase = (LAYER == 1 && dir) ? ((T_STEPS - 1 - t) * 64 + row0) : (t * 64 + row0);
#pragma unroll
    for (int j = 0; j < 2; ++j) {
      f32x4 ac = j ? accB1 : accB0;
      f32x4 xv = j ? xb1 : xb0;
      int c2 = (w * 2 + j) * 16 + ccol;    // cand col 0..255
#pragma unroll
      for (int r = 0; r < 4; ++r) {
        int rr = crow + r;
        float v = ac[r] + xv[r];
        float cand = __builtin_amdgcn_rcpf(1.0f + __builtin_amdgcn_exp2f(v)) * 2.0f - 1.0f;
        _Float16 zh = __builtin_bit_cast(_Float16, z_h[rr * 256 + c2]);
        float z = (float)zh;
        float h = hreg[j][r];
        float hn = cand + z * (h - cand);
        hreg[j][r] = hn;
        int cb = c2 * 2;
        int byt = rr * 512 + (((cb & ~15) ^ ((rr & 7) << 4)) | (cb & 15));
        *(unsigned short*)((char*)h_bf + byt) = f2bf(hn);
        if (LAYER == 0) sp_bf[(size_t)(gbase + rr) * 256 + c2] = f2bf(hn);
        else            out[(size_t)(gbase + rr) * 512 + coff + c2] = hn;
      }
    }
    asm volatile("s_waitcnt lgkmcnt(0)" ::: "memory", ACLB);
    __builtin_amdgcn_s_barrier();
  }

  // persist h; on last chunk also write fh/bh
#pragma unroll
  for (int j = 0; j < 2; ++j)
#pragma unroll
    for (int r = 0; r < 4; ++r) {
      int rr = crow + r, c = (w * 2 + j) * 16 + ccol;
      hst[rr * 256 + c] = hreg[j][r];
      if (t0 + chunkT == T_STEPS) {
        float* dst = dout_h + (dir ? 32768 : 0) + (size_t)LAYER * 16384;
        dst[(size_t)(row0 + rr) * 256 + c] = hreg[j][r];
      }
    }
}

__global__ void diag_kernel(float* out, float v) { out[0] = v; }

// --------------------------------------------------------------------------------------
extern "C" void kernel_launch(void* const* d_in, const int* in_sizes, int n_in,
                              void* d_out, int out_size, void* d_ws, size_t ws_size,
                              hipStream_t stream) {
  const float* x     = (const float*)d_in[0];
  const float* fw_W0 = (const float*)d_in[2];
  const float* fw_b0 = (const float*)d_in[3];
  const float* fw_W1 = (const float*)d_in[4];
  const float* fw_b1 = (const float*)d_in[5];
  const float* bw_W0 = (const float*)d_in[6];
  const float* bw_b0 = (const float*)d_in[7];
  const float* bw_W1 = (const float*)d_in[8];
  const float* bw_b1 = (const float*)d_in[9];

  char* ws = (char*)d_ws;
  size_t off = 0;
  auto alloc = [&](size_t bytes) -> char* {
    char* p = ws + off; off += (bytes + 255) & ~(size_t)255; return p;
  };
  unsigned short* Wx0p  = (unsigned short*)alloc(2ull * 48 * 8 * 64 * 8 * 2);
  unsigned short* Wx1p  = (unsigned short*)alloc(2ull * 48 * 16 * 64 * 8 * 2);
  unsigned short* Whrz0 = (unsigned short*)alloc(2ull * 32 * 8 * 64 * 8 * 2);
  unsigned short* Whc0  = (unsigned short*)alloc(2ull * 16 * 8 * 64 * 8 * 2);
  unsigned short* Whrz1 = (unsigned short*)alloc(2ull * 32 * 8 * 64 * 8 * 2);
  unsigned short* Whc1  = (unsigned short*)alloc(2ull * 16 * 8 * 64 * 8 * 2);
  unsigned short* fs0   = (unsigned short*)alloc((size_t)TB * 256 * 2);
  unsigned short* bs0   = (unsigned short*)alloc((size_t)TB * 256 * 2);
  float* hstate         = (float*)alloc(2ull * 4 * 16 * 256 * 4);

  int chunkT = 0;
  for (int ct = 128; ct >= 8; ct >>= 1) {
    if (off + (size_t)ct * 2 * 64 * 768 * 4 <= ws_size) { chunkT = ct; break; }
  }
  float* out = (float*)d_out;
  if (chunkT == 0) {
    diag_kernel<<<1, 1, 0, stream>>>(out, 12345.0f);
    return;
  }
  f32x4* Xg = (f32x4*)alloc((size_t)chunkT * 2 * 64 * 768 * 4);
  float* dout_h = out + (size_t)TB * 512;

  auto packw = [&](const float* W, int rows, int kb, int ntl, int ktl, int mode, unsigned short* dst) {
    int total = ntl * ktl * 64;
    pack_w_kernel<<<(total + 255) / 256, 256, 0, stream>>>(W, rows, kb, ntl, ktl, mode, dst);
  };
  packw(fw_W0, 512, 0,   48, 8,  0, Wx0p);
  packw(bw_W0, 512, 0,   48, 8,  0, Wx0p + 48 * 8 * 64 * 8);
  packw(fw_W1, 768, 0,   48, 16, 0, Wx1p);
  packw(bw_W1, 768, 0,   48, 16, 0, Wx1p + 48 * 16 * 64 * 8);
  packw(fw_W0, 512, 256, 32, 8,  1, Whrz0);
  packw(bw_W0, 512, 256, 32, 8,  1, Whrz0 + 32 * 8 * 64 * 8);
  packw(fw_W0, 512, 256, 16, 8,  2, Whc0);
  packw(bw_W0, 512, 256, 16, 8,  2, Whc0 + 16 * 8 * 64 * 8);
  packw(fw_W1, 768, 512, 32, 8,  1, Whrz1);
  packw(bw_W1, 768, 512, 32, 8,  1, Whrz1 + 32 * 8 * 64 * 8);
  packw(fw_W1, 768, 512, 16, 8,  2, Whc1);
  packw(bw_W1, 768, 512, 16, 8,  2, Whc1 + 16 * 8 * 64 * 8);

  dim3 rgrid(4, 2);
  // layer 0
  for (int t0 = 0; t0 < T_STEPS; t0 += chunkT) {
    dim3 ggrid(chunkT / 2, 6, 2);
    gemm_xg_kernel<0><<<ggrid, 256, 0, stream>>>(x, nullptr, nullptr, Wx0p, fw_b0, bw_b0, Xg, t0, chunkT);
    gru_kernel<0><<<rgrid, 512, 0, stream>>>(Xg,
        (const uint4*)Whrz0, (const uint4*)(Whrz0 + 32 * 8 * 64 * 8),
        (const uint4*)Whc0,  (const uint4*)(Whc0 + 16 * 8 * 64 * 8),
        fs0, bs0, nullptr, hstate, dout_h, t0, chunkT);
  }
  // layer 1
  for (int t0 = 0; t0 < T_STEPS; t0 += chunkT) {
    dim3 ggrid(chunkT / 2, 6, 2);
    gemm_xg_kernel<1><<<ggrid, 256, 0, stream>>>(nullptr, fs0, bs0, Wx1p, fw_b1, bw_b1, Xg, t0, chunkT);
    gru_kernel<1><<<rgrid, 512, 0, stream>>>(Xg,
        (const uint4*)Whrz1, (const uint4*)(Whrz1 + 32 * 8 * 64 * 8),
        (const uint4*)Whc1,  (const uint4*)(Whc1 + 16 * 8 * 64 * 8),
        nullptr, nullptr, out, hstate, dout_h, t0, chunkT);
  }
}

// Round 9
// 2911.012 us; speedup vs baseline: 1.4672x; 1.4672x over previous
//
#include <hip/hip_runtime.h>
#include <hip/hip_bf16.h>

#define T_STEPS 512
#define BATCH 64
#define TB (T_STEPS * BATCH)   // 32768

typedef short bf16x8 __attribute__((ext_vector_type(8)));
typedef float f32x4 __attribute__((ext_vector_type(4)));

union FragU { uint4 u; bf16x8 v; };

static __device__ __forceinline__ bf16x8 ld_frag(const uint4* p) {
  FragU f; f.u = *p; return f.v;
}

static __device__ __forceinline__ unsigned short f2bf(float f) {
  unsigned u = __float_as_uint(f);
  return (unsigned short)((u + 0x7FFFu + ((u >> 16) & 1u)) >> 16);
}

static __device__ __forceinline__ int revrow(int r) {
  int t = r >> 6, b = r & 63;
  return ((T_STEPS - 1 - t) << 6) | b;
}

#define S_RZ  (-1.4426950408889634f)   /* -log2(e)   : sigmoid(p)=1/(1+2^(S_RZ*p)) */
#define S_C   (-2.8853900817779268f)   /* -2*log2(e) : tanh(p)=2/(1+2^(S_C*p))-1   */

// ---- explicit named-AGPR weight residency (round-8-validated) ------------------------
#define AWR(N, x) asm volatile("v_accvgpr_write_b32 a" #N ", %0" :: "v"(x) : "a" #N)
// frag F (0..31): chain c=F>>3 -> acc chain, kt=F&7. chain 0,1 = r-tiles 2w,2w+1;
// chain 2,3 = z-tiles 16+2w,17+2w  (wave's own cand columns -> z stays in registers)
#define LOADF(F, A0, A1, A2, A3) do { \
    const int c_ = (F) >> 3, kt_ = (F) & 7; \
    const int nt_ = (c_ < 2) ? (w * 2 + c_) : (14 + w * 2 + c_); \
    uint4 t = whrzp[((size_t)nt_ * 8 + kt_) * 64 + lane]; \
    AWR(A0, t.x); AWR(A1, t.y); AWR(A2, t.z); AWR(A3, t.w); } while (0)

#define MFMA_A(acc, va, B0, B3) \
  asm volatile("v_mfma_f32_16x16x32_bf16 %0, %1, a[" #B0 ":" #B3 "], %0" \
               : "+v"(acc) : "v"(va))
#define MFMA_A1(acc, va, B0, B3) \
  asm volatile("s_nop 1\n\tv_mfma_f32_16x16x32_bf16 %0, %1, a[" #B0 ":" #B3 "], %0" \
               : "+v"(acc) : "v"(va))
#define MFMA_V(acc, va, vb) \
  asm volatile("v_mfma_f32_16x16x32_bf16 %0, %1, %2, %0" \
               : "+v"(acc) : "v"(va), "v"(vb))
#define MFMA_V1(acc, va, vb) \
  asm volatile("s_nop 1\n\tv_mfma_f32_16x16x32_bf16 %0, %1, %2, %0" \
               : "+v"(acc) : "v"(va), "v"(vb))
#define ACCFENCE(acc) asm volatile("s_nop 7\n\ts_nop 7" : "+v"(acc))

#define ACLB \
  "a0","a1","a2","a3","a4","a5","a6","a7","a8","a9","a10","a11","a12","a13","a14","a15", \
  "a16","a17","a18","a19","a20","a21","a22","a23","a24","a25","a26","a27","a28","a29","a30","a31", \
  "a32","a33","a34","a35","a36","a37","a38","a39","a40","a41","a42","a43","a44","a45","a46","a47", \
  "a48","a49","a50","a51","a52","a53","a54","a55","a56","a57","a58","a59","a60","a61","a62","a63", \
  "a64","a65","a66","a67","a68","a69","a70","a71","a72","a73","a74","a75","a76","a77","a78","a79", \
  "a80","a81","a82","a83","a84","a85","a86","a87","a88","a89","a90","a91","a92","a93","a94","a95", \
  "a96","a97","a98","a99","a100","a101","a102","a103","a104","a105","a106","a107","a108","a109","a110","a111", \
  "a112","a113","a114","a115","a116","a117","a118","a119","a120","a121","a122","a123","a124","a125","a126","a127"

// ---------------- pack weights into MFMA B-fragment layout (with gate pre-scaling) ----
__global__ void pack_w_kernel(const float* __restrict__ W, int rows, int k_base,
                              int n_tiles, int k_tiles, int mode,
                              unsigned short* __restrict__ dst) {
  int gid = blockIdx.x * blockDim.x + threadIdx.x;
  int total = n_tiles * k_tiles * 64;
  if (gid >= total) return;
  int lane = gid & 63;
  int fi = gid >> 6;
  int kt = fi % k_tiles;
  int nt = fi / k_tiles;
  int n = nt * 16 + (lane & 15);
  int g, col; float s;
  if (mode == 0)      { g = n >> 8;            col = n & 255; s = (g == 1) ? S_C : S_RZ; }
  else if (mode == 1) { g = (n < 256) ? 0 : 2; col = n & 255; s = S_RZ; }
  else                { g = 1;                 col = n;       s = S_C; }
  int k0 = k_base + kt * 32 + ((lane >> 4) << 3);
  const float* src = W + ((size_t)g * rows + k0) * 256 + col;
  unsigned short v[8];
#pragma unroll
  for (int j = 0; j < 8; ++j) v[j] = f2bf(src[(size_t)j * 256] * s);
  uint4 o;
  o.x = v[0] | ((unsigned)v[1] << 16);
  o.y = v[2] | ((unsigned)v[3] << 16);
  o.z = v[4] | ((unsigned)v[5] << 16);
  o.w = v[6] | ((unsigned)v[7] << 16);
  ((uint4*)dst)[gid] = o;
}

static __device__ __forceinline__ bf16x8 cvt8(float4 f0, float4 f1) {
  uint4 o;
  o.x = f2bf(f0.x) | ((unsigned)f2bf(f0.y) << 16);
  o.y = f2bf(f0.z) | ((unsigned)f2bf(f0.w) << 16);
  o.z = f2bf(f1.x) | ((unsigned)f2bf(f1.y) << 16);
  o.w = f2bf(f1.z) | ((unsigned)f2bf(f1.w) << 16);
  FragU f; f.u = o; return f.v;
}

// ---------------- Xg GEMM (chunked): writes C-fragment tile layout --------------------
template<int LAYER>
__global__ __launch_bounds__(256)
void gemm_xg_kernel(const float* __restrict__ x,
                    const unsigned short* __restrict__ fs0,
                    const unsigned short* __restrict__ bs0,
                    const unsigned short* __restrict__ Bp,
                    const float* __restrict__ bias_fw,
                    const float* __restrict__ bias_bw,
                    f32x4* __restrict__ Xg, int t0, int chunkT)
{
  constexpr int KT = (LAYER == 0) ? 8 : 16;
  int dir = blockIdx.z;
  int lane = threadIdx.x & 63;
  int w = threadIdx.x >> 6;
  int ww = w >> 1, wc = w & 1;
  int mt0 = blockIdx.x * 8 + ww * 4;
  int nt0 = blockIdx.y * 8 + wc * 4;
  const uint4* B = (const uint4*)Bp + (size_t)dir * 48 * KT * 64;
  const int arow = lane & 15;
  const int k0b = ((lane >> 4) << 3);

  f32x4 acc[4][4] = {};
#pragma unroll
  for (int kt = 0; kt < KT; ++kt) {
    int k0 = kt * 32 + k0b;
    bf16x8 a[4], b[4];
#pragma unroll
    for (int i = 0; i < 4; ++i) {
      int grow = t0 * 64 + (mt0 + i) * 16 + arow;
      if (LAYER == 0) {
        int gr = dir ? revrow(grow) : grow;
        const float4* s = (const float4*)(x + (size_t)gr * 256 + k0);
        a[i] = cvt8(s[0], s[1]);
      } else {
        const unsigned short* base; int r2 = grow, kk = k0;
        if (k0 < 256) { base = dir ? bs0 : fs0; }
        else          { base = dir ? fs0 : bs0; r2 = revrow(grow); kk = k0 - 256; }
        a[i] = *(const bf16x8*)(base + (size_t)r2 * 256 + kk);
      }
    }
#pragma unroll
    for (int j = 0; j < 4; ++j) b[j] = ld_frag(B + ((size_t)(nt0 + j) * KT + kt) * 64 + lane);
#pragma unroll
    for (int i = 0; i < 4; ++i)
#pragma unroll
      for (int j = 0; j < 4; ++j)
        acc[i][j] = __builtin_amdgcn_mfma_f32_16x16x32_bf16(a[i], b[j], acc[i][j], 0, 0, 0);
  }

  const float* bias = dir ? bias_bw : bias_fw;
  f32x4* C = Xg + (size_t)dir * (chunkT * 4) * 48 * 64;
#pragma unroll
  for (int j = 0; j < 4; ++j) {
    int ct = nt0 + j;
    int col = ct * 16 + (lane & 15);
    int g = col >> 8, cc = col & 255;
    float bv = ((g == 1) ? S_C : S_RZ) * bias[g * 256 + cc];
#pragma unroll
    for (int i = 0; i < 4; ++i) {
      int rt = blockIdx.x * 8 + ww * 4 + i;
      f32x4 v = acc[i][j];
      v[0] += bv; v[1] += bv; v[2] += bv; v[3] += bv;
      C[((size_t)rt * 48 + ct) * 64 + lane] = v;
    }
  }
}

// ---------------- persistent recurrent GRU kernel (one layer, both dirs, chunked) -----
// grid (4, 2), 512 threads = 8 waves. Whrz in physical a0..a127; Whc in LDS.
// Wave w owns r-tiles {2w,2w+1} AND z-tiles {16+2w,17+2w} (its own cand cols):
// z + h stay in registers; only rh/h bf16 A-fragments go through LDS.
// Xg double-buffered across steps in registers (prefetch after phase-B MFMA wall).
template<int LAYER>
__global__ __launch_bounds__(512) __attribute__((amdgpu_waves_per_eu(2, 2)))
void gru_kernel(const f32x4* __restrict__ Xg,
                const uint4* __restrict__ whrz_fw, const uint4* __restrict__ whrz_bw, // [32][8][64]
                const uint4* __restrict__ whc_fw,  const uint4* __restrict__ whc_bw,  // [16][8][64]
                unsigned short* __restrict__ sfw_bf, unsigned short* __restrict__ sbw_bf,
                float* __restrict__ out,
                float* __restrict__ hstate, float* __restrict__ dout_h,
                int t0, int chunkT)
{
  const int dir = blockIdx.y;
  const int bx = blockIdx.x;
  const int row0 = bx * 16;
  const int tid = threadIdx.x;
  const int lane = tid & 63;
  const int w = tid >> 6;               // 0..7

  __shared__ __align__(16) unsigned short h_bf[16 * 256];   // swizzled bf16 h       (8 KB)
  __shared__ __align__(16) unsigned short rh_bf[16 * 256];  // swizzled bf16 r*h     (8 KB)
  __shared__ __align__(16) uint4 wc_lds[16 * 8 * 64];       // Whc B-fragments     (128 KB)

  const uint4* whrzp = dir ? whrz_bw : whrz_fw;
  const uint4* whcp  = dir ? whc_bw  : whc_fw;

  // stage Whc into LDS
  for (int i = tid; i < 16 * 8 * 64; i += 512) wc_lds[i] = whcp[i];

  // pin Whrz fragments into physical a0..a127 (chain remap per wave, see LOADF)
  LOADF(0, 0, 1, 2, 3);     LOADF(1, 4, 5, 6, 7);     LOADF(2, 8, 9, 10, 11);   LOADF(3, 12, 13, 14, 15);
  LOADF(4, 16, 17, 18, 19); LOADF(5, 20, 21, 22, 23); LOADF(6, 24, 25, 26, 27); LOADF(7, 28, 29, 30, 31);
  LOADF(8, 32, 33, 34, 35); LOADF(9, 36, 37, 38, 39); LOADF(10, 40, 41, 42, 43); LOADF(11, 44, 45, 46, 47);
  LOADF(12, 48, 49, 50, 51); LOADF(13, 52, 53, 54, 55); LOADF(14, 56, 57, 58, 59); LOADF(15, 60, 61, 62, 63);
  LOADF(16, 64, 65, 66, 67); LOADF(17, 68, 69, 70, 71); LOADF(18, 72, 73, 74, 75); LOADF(19, 76, 77, 78, 79);
  LOADF(20, 80, 81, 82, 83); LOADF(21, 84, 85, 86, 87); LOADF(22, 88, 89, 90, 91); LOADF(23, 92, 93, 94, 95);
  LOADF(24, 96, 97, 98, 99); LOADF(25, 100, 101, 102, 103); LOADF(26, 104, 105, 106, 107); LOADF(27, 108, 109, 110, 111);
  LOADF(28, 112, 113, 114, 115); LOADF(29, 116, 117, 118, 119); LOADF(30, 120, 121, 122, 123); LOADF(31, 124, 125, 126, 127);

  const int ccol = lane & 15;
  const int crow = ((lane >> 4) << 2);     // 0,4,8,12

  float* hst = hstate + (size_t)(dir * 4 + bx) * 4096;
  for (int i = tid; i < 16 * 256; i += 512) {
    float v = (t0 == 0) ? 0.0f : hst[i];
    int rr = i >> 8, cc = i & 255;
    int cb = cc * 2;
    int byt = rr * 512 + (((cb & ~15) ^ ((rr & 7) << 4)) | (cb & 15));
    *(unsigned short*)((char*)h_bf + byt) = f2bf(v);
  }
  float hreg[2][4];
#pragma unroll
  for (int j = 0; j < 2; ++j)
#pragma unroll
    for (int r = 0; r < 4; ++r) {
      int rr = crow + r, c = (w * 2 + j) * 16 + ccol;
      hreg[j][r] = (t0 == 0) ? 0.0f : hst[rr * 256 + c];
    }
  __syncthreads();

  // Xg column-tiles: r accs {2w,2w+1}, z accs {32+2w,33+2w}, cand {16+2w,17+2w}
  const int ctR0 = w * 2, ctR1 = w * 2 + 1;
  const int ctZ0 = 32 + w * 2, ctZ1 = 33 + w * 2;
  const int ctB0c = 16 + w * 2, ctB1c = 17 + w * 2;
  const f32x4* XgD = Xg + (size_t)dir * (chunkT * 4) * 48 * 64;
  unsigned short* sp_bf = dir ? sbw_bf : sfw_bf;
  const int coff = dir ? 256 : 0;
  const int ardbase = (lane & 15) * 512;
  const int arxor = ((lane & 7) << 4);
  const int afc = ((lane >> 4) << 4);

#define AFRAG(KT) (*(const bf16x8*)((const char*)h_bf + (ardbase + ((KT * 64 + afc) ^ arxor))))
#define RFRAG(KT) (*(const bf16x8*)((const char*)rh_bf + (ardbase + ((KT * 64 + afc) ^ arxor))))

  // prologue: load step-0 Xg into the double-buffer registers
  f32x4 xa0, xa1, xa2, xa3, xb0, xb1;
  {
    size_t rtb0 = ((size_t)(0 * 4 + bx) * 48) * 64 + lane;
    xa0 = XgD[rtb0 + (size_t)ctR0 * 64];
    xa1 = XgD[rtb0 + (size_t)ctR1 * 64];
    xa2 = XgD[rtb0 + (size_t)ctZ0 * 64];
    xa3 = XgD[rtb0 + (size_t)ctZ1 * 64];
    xb0 = XgD[rtb0 + (size_t)ctB0c * 64];
    xb1 = XgD[rtb0 + (size_t)ctB1c * 64];
  }

#pragma unroll 1
  for (int t = t0; t < t0 + chunkT; ++t) {
    const int tloc = t - t0;

    // ---------- phase A: rz = h @ Whrz (+x-part), weights from pinned AGPRs ----------
    f32x4 accA0 = {}, accA1 = {}, accA2 = {}, accA3 = {};
    {
      bf16x8 af;
      af = AFRAG(0);
      MFMA_A1(accA0, af, 0, 3);   MFMA_A1(accA1, af, 32, 35);
      MFMA_A1(accA2, af, 64, 67); MFMA_A1(accA3, af, 96, 99);
      af = AFRAG(1);
      MFMA_A(accA0, af, 4, 7);    MFMA_A(accA1, af, 36, 39);
      MFMA_A(accA2, af, 68, 71);  MFMA_A(accA3, af, 100, 103);
      af = AFRAG(2);
      MFMA_A(accA0, af, 8, 11);   MFMA_A(accA1, af, 40, 43);
      MFMA_A(accA2, af, 72, 75);  MFMA_A(accA3, af, 104, 107);
      af = AFRAG(3);
      MFMA_A(accA0, af, 12, 15);  MFMA_A(accA1, af, 44, 47);
      MFMA_A(accA2, af, 76, 79);  MFMA_A(accA3, af, 108, 111);
      af = AFRAG(4);
      MFMA_A(accA0, af, 16, 19);  MFMA_A(accA1, af, 48, 51);
      MFMA_A(accA2, af, 80, 83);  MFMA_A(accA3, af, 112, 115);
      af = AFRAG(5);
      MFMA_A(accA0, af, 20, 23);  MFMA_A(accA1, af, 52, 55);
      MFMA_A(accA2, af, 84, 87);  MFMA_A(accA3, af, 116, 119);
      af = AFRAG(6);
      MFMA_A(accA0, af, 24, 27);  MFMA_A(accA1, af, 56, 59);
      MFMA_A(accA2, af, 88, 91);  MFMA_A(accA3, af, 120, 123);
      af = AFRAG(7);
      MFMA_A(accA0, af, 28, 31);  MFMA_A(accA1, af, 60, 63);
      MFMA_A(accA2, af, 92, 95);  MFMA_A(accA3, af, 124, 127);
    }
    ACCFENCE(accA0); ACCFENCE(accA1); ACCFENCE(accA2); ACCFENCE(accA3);

    // epilogue A: r-gates -> rh_bf (LDS); z-gates -> zreg (registers)
    float zreg[2][4];
#pragma unroll
    for (int j = 0; j < 2; ++j) {
      f32x4 ac = j ? accA1 : accA0;
      f32x4 xv = j ? xa1 : xa0;
      int cl = (w * 2 + j) * 16 + ccol;
#pragma unroll
      for (int r = 0; r < 4; ++r) {
        int rr = crow + r;
        float v = ac[r] + xv[r];
        float gate = __builtin_amdgcn_rcpf(1.0f + __builtin_amdgcn_exp2f(v)); // sigmoid(r)
        int cb = cl * 2;
        int byt = rr * 512 + (((cb & ~15) ^ ((rr & 7) << 4)) | (cb & 15));
        *(unsigned short*)((char*)rh_bf + byt) = f2bf(gate * hreg[j][r]);
      }
    }
#pragma unroll
    for (int j = 0; j < 2; ++j) {
      f32x4 ac = j ? accA3 : accA2;
      f32x4 xv = j ? xa3 : xa2;
#pragma unroll
      for (int r = 0; r < 4; ++r) {
        float v = ac[r] + xv[r];
        zreg[j][r] = __builtin_amdgcn_rcpf(1.0f + __builtin_amdgcn_exp2f(v)); // sigmoid(z)
      }
    }
    asm volatile("s_waitcnt lgkmcnt(0)" ::: "memory", ACLB);
    __builtin_amdgcn_s_barrier();

    // ---------- phase B: cand = tanh-form((r*h) @ Whc + x-part), update h ----------
    f32x4 accB0 = {}, accB1 = {};
#pragma unroll
    for (int kt = 0; kt < 8; ++kt) {
      bf16x8 a = RFRAG(kt);
      bf16x8 b0 = *(const bf16x8*)&wc_lds[((size_t)(w * 2 + 0) * 8 + kt) * 64 + lane];
      bf16x8 b1 = *(const bf16x8*)&wc_lds[((size_t)(w * 2 + 1) * 8 + kt) * 64 + lane];
      if (kt == 0) { MFMA_V1(accB0, a, b0); MFMA_V1(accB1, a, b1); }
      else         { MFMA_V(accB0, a, b0);  MFMA_V(accB1, a, b1); }
    }
    // capture current-step cand x-parts, then prefetch next step's Xg (hidden under
    // epilogue B + barrier + next phase A)
    f32x4 cb0 = xb0, cb1 = xb1;
    {
      int tn = (tloc + 1 < chunkT) ? tloc + 1 : tloc;
      size_t rtn = ((size_t)(tn * 4 + bx) * 48) * 64 + lane;
      xa0 = XgD[rtn + (size_t)ctR0 * 64];
      xa1 = XgD[rtn + (size_t)ctR1 * 64];
      xa2 = XgD[rtn + (size_t)ctZ0 * 64];
      xa3 = XgD[rtn + (size_t)ctZ1 * 64];
      xb0 = XgD[rtn + (size_t)ctB0c * 64];
      xb1 = XgD[rtn + (size_t)ctB1c * 64];
    }
    ACCFENCE(accB0); ACCFENCE(accB1);
    int gbase = (LAYER == 1 && dir) ? ((T_STEPS - 1 - t) * 64 + row0) : (t * 64 + row0);
#pragma unroll
    for (int j = 0; j < 2; ++j) {
      f32x4 ac = j ? accB1 : accB0;
      f32x4 xv = j ? cb1 : cb0;
      int c2 = (w * 2 + j) * 16 + ccol;
#pragma unroll
      for (int r = 0; r < 4; ++r) {
        int rr = crow + r;
        float v = ac[r] + xv[r];
        float cand = __builtin_amdgcn_rcpf(1.0f + __builtin_amdgcn_exp2f(v)) * 2.0f - 1.0f;
        float z = zreg[j][r];
        float h = hreg[j][r];
        float hn = cand + z * (h - cand);
        hreg[j][r] = hn;
        int cb = c2 * 2;
        int byt = rr * 512 + (((cb & ~15) ^ ((rr & 7) << 4)) | (cb & 15));
        *(unsigned short*)((char*)h_bf + byt) = f2bf(hn);
        if (LAYER == 0) sp_bf[(size_t)(gbase + rr) * 256 + c2] = f2bf(hn);
        else            out[(size_t)(gbase + rr) * 512 + coff + c2] = hn;
      }
    }
    asm volatile("s_waitcnt lgkmcnt(0)" ::: "memory", ACLB);
    __builtin_amdgcn_s_barrier();
  }

  // persist h; on last chunk also write fh/bh
#pragma unroll
  for (int j = 0; j < 2; ++j)
#pragma unroll
    for (int r = 0; r < 4; ++r) {
      int rr = crow + r, c = (w * 2 + j) * 16 + ccol;
      hst[rr * 256 + c] = hreg[j][r];
      if (t0 + chunkT == T_STEPS) {
        float* dst = dout_h + (dir ? 32768 : 0) + (size_t)LAYER * 16384;
        dst[(size_t)(row0 + rr) * 256 + c] = hreg[j][r];
      }
    }
}

__global__ void diag_kernel(float* out, float v) { out[0] = v; }

// --------------------------------------------------------------------------------------
extern "C" void kernel_launch(void* const* d_in, const int* in_sizes, int n_in,
                              void* d_out, int out_size, void* d_ws, size_t ws_size,
                              hipStream_t stream) {
  const float* x     = (const float*)d_in[0];
  const float* fw_W0 = (const float*)d_in[2];
  const float* fw_b0 = (const float*)d_in[3];
  const float* fw_W1 = (const float*)d_in[4];
  const float* fw_b1 = (const float*)d_in[5];
  const float* bw_W0 = (const float*)d_in[6];
  const float* bw_b0 = (const float*)d_in[7];
  const float* bw_W1 = (const float*)d_in[8];
  const float* bw_b1 = (const float*)d_in[9];

  char* ws = (char*)d_ws;
  size_t off = 0;
  auto alloc = [&](size_t bytes) -> char* {
    char* p = ws + off; off += (bytes + 255) & ~(size_t)255; return p;
  };
  unsigned short* Wx0p  = (unsigned short*)alloc(2ull * 48 * 8 * 64 * 8 * 2);
  unsigned short* Wx1p  = (unsigned short*)alloc(2ull * 48 * 16 * 64 * 8 * 2);
  unsigned short* Whrz0 = (unsigned short*)alloc(2ull * 32 * 8 * 64 * 8 * 2);
  unsigned short* Whc0  = (unsigned short*)alloc(2ull * 16 * 8 * 64 * 8 * 2);
  unsigned short* Whrz1 = (unsigned short*)alloc(2ull * 32 * 8 * 64 * 8 * 2);
  unsigned short* Whc1  = (unsigned short*)alloc(2ull * 16 * 8 * 64 * 8 * 2);
  unsigned short* fs0   = (unsigned short*)alloc((size_t)TB * 256 * 2);
  unsigned short* bs0   = (unsigned short*)alloc((size_t)TB * 256 * 2);
  float* hstate         = (float*)alloc(2ull * 4 * 16 * 256 * 4);

  int chunkT = 0;
  for (int ct = 128; ct >= 8; ct >>= 1) {
    if (off + (size_t)ct * 2 * 64 * 768 * 4 <= ws_size) { chunkT = ct; break; }
  }
  float* out = (float*)d_out;
  if (chunkT == 0) {
    diag_kernel<<<1, 1, 0, stream>>>(out, 12345.0f);
    return;
  }
  f32x4* Xg = (f32x4*)alloc((size_t)chunkT * 2 * 64 * 768 * 4);
  float* dout_h = out + (size_t)TB * 512;

  auto packw = [&](const float* W, int rows, int kb, int ntl, int ktl, int mode, unsigned short* dst) {
    int total = ntl * ktl * 64;
    pack_w_kernel<<<(total + 255) / 256, 256, 0, stream>>>(W, rows, kb, ntl, ktl, mode, dst);
  };
  packw(fw_W0, 512, 0,   48, 8,  0, Wx0p);
  packw(bw_W0, 512, 0,   48, 8,  0, Wx0p + 48 * 8 * 64 * 8);
  packw(fw_W1, 768, 0,   48, 16, 0, Wx1p);
  packw(bw_W1, 768, 0,   48, 16, 0, Wx1p + 48 * 16 * 64 * 8);
  packw(fw_W0, 512, 256, 32, 8,  1, Whrz0);
  packw(bw_W0, 512, 256, 32, 8,  1, Whrz0 + 32 * 8 * 64 * 8);
  packw(fw_W0, 512, 256, 16, 8,  2, Whc0);
  packw(bw_W0, 512, 256, 16, 8,  2, Whc0 + 16 * 8 * 64 * 8);
  packw(fw_W1, 768, 512, 32, 8,  1, Whrz1);
  packw(bw_W1, 768, 512, 32, 8,  1, Whrz1 + 32 * 8 * 64 * 8);
  packw(fw_W1, 768, 512, 16, 8,  2, Whc1);
  packw(bw_W1, 768, 512, 16, 8,  2, Whc1 + 16 * 8 * 64 * 8);

  dim3 rgrid(4, 2);
  // layer 0
  for (int t0 = 0; t0 < T_STEPS; t0 += chunkT) {
    dim3 ggrid(chunkT / 2, 6, 2);
    gemm_xg_kernel<0><<<ggrid, 256, 0, stream>>>(x, nullptr, nullptr, Wx0p, fw_b0, bw_b0, Xg, t0, chunkT);
    gru_kernel<0><<<rgrid, 512, 0, stream>>>(Xg,
        (const uint4*)Whrz0, (const uint4*)(Whrz0 + 32 * 8 * 64 * 8),
        (const uint4*)Whc0,  (const uint4*)(Whc0 + 16 * 8 * 64 * 8),
        fs0, bs0, nullptr, hstate, dout_h, t0, chunkT);
  }
  // layer 1
  for (int t0 = 0; t0 < T_STEPS; t0 += chunkT) {
    dim3 ggrid(chunkT / 2, 6, 2);
    gemm_xg_kernel<1><<<ggrid, 256, 0, stream>>>(nullptr, fs0, bs0, Wx1p, fw_b1, bw_b1, Xg, t0, chunkT);
    gru_kernel<1><<<rgrid, 512, 0, stream>>>(Xg,
        (const uint4*)Whrz1, (const uint4*)(Whrz1 + 32 * 8 * 64 * 8),
        (const uint4*)Whc1,  (const uint4*)(Whc1 + 16 * 8 * 64 * 8),
        nullptr, nullptr, out, hstate, dout_h, t0, chunkT);
  }
}

// Round 10
// 2549.988 us; speedup vs baseline: 1.6750x; 1.1416x over previous
//
#include <hip/hip_runtime.h>
#include <hip/hip_bf16.h>

#define T_STEPS 512
#define BATCH 64
#define TB (T_STEPS * BATCH)   // 32768

typedef short bf16x8 __attribute__((ext_vector_type(8)));
typedef float f32x4 __attribute__((ext_vector_type(4)));

union FragU { uint4 u; bf16x8 v; };

static __device__ __forceinline__ bf16x8 ld_frag(const uint4* p) {
  FragU f; f.u = *p; return f.v;
}

static __device__ __forceinline__ unsigned short f2bf(float f) {
  unsigned u = __float_as_uint(f);
  return (unsigned short)((u + 0x7FFFu + ((u >> 16) & 1u)) >> 16);
}

// packed f32->bf16 (RNE), 1 inst per pair
static __device__ __forceinline__ unsigned cvt_pk_bf16(float lo, float hi) {
  unsigned r;
  asm("v_cvt_pk_bf16_f32 %0, %1, %2" : "=v"(r) : "v"(lo), "v"(hi));
  return r;
}

static __device__ __forceinline__ int revrow(int r) {
  int t = r >> 6, b = r & 63;
  return ((T_STEPS - 1 - t) << 6) | b;
}

#define S_RZ  (-1.4426950408889634f)   /* -log2(e)   : sigmoid(p)=1/(1+2^(S_RZ*p)) */
#define S_C   (-2.8853900817779268f)   /* -2*log2(e) : tanh(p)=2/(1+2^(S_C*p))-1   */

// ---- explicit named-AGPR weight residency (round-8/9-validated) ----------------------
#define AWR(N, x) asm volatile("v_accvgpr_write_b32 a" #N ", %0" :: "v"(x) : "a" #N)
#define LOADF(F, A0, A1, A2, A3) do { \
    const int c_ = (F) >> 3, kt_ = (F) & 7; \
    const int nt_ = (c_ < 2) ? (w * 2 + c_) : (14 + w * 2 + c_); \
    uint4 t = whrzp[((size_t)nt_ * 8 + kt_) * 64 + lane]; \
    AWR(A0, t.x); AWR(A1, t.y); AWR(A2, t.z); AWR(A3, t.w); } while (0)

#define MFMA_A(acc, va, B0, B3) \
  asm volatile("v_mfma_f32_16x16x32_bf16 %0, %1, a[" #B0 ":" #B3 "], %0" \
               : "+v"(acc) : "v"(va))
#define MFMA_A1(acc, va, B0, B3) \
  asm volatile("s_nop 1\n\tv_mfma_f32_16x16x32_bf16 %0, %1, a[" #B0 ":" #B3 "], %0" \
               : "+v"(acc) : "v"(va))
#define MFMA_V(acc, va, vb) \
  asm volatile("v_mfma_f32_16x16x32_bf16 %0, %1, %2, %0" \
               : "+v"(acc) : "v"(va), "v"(vb))
#define MFMA_V1(acc, va, vb) \
  asm volatile("s_nop 1\n\tv_mfma_f32_16x16x32_bf16 %0, %1, %2, %0" \
               : "+v"(acc) : "v"(va), "v"(vb))
// fences before VALU reads of MFMA results (16 wait-state slots, shared per group)
#define ACCFENCE2(a, b) asm volatile("s_nop 7\n\ts_nop 7" : "+v"(a), "+v"(b))
#define ACCFENCE4(a, b, c, d) \
  asm volatile("s_nop 7\n\ts_nop 7" : "+v"(a), "+v"(b), "+v"(c), "+v"(d))

#define ACLB \
  "a0","a1","a2","a3","a4","a5","a6","a7","a8","a9","a10","a11","a12","a13","a14","a15", \
  "a16","a17","a18","a19","a20","a21","a22","a23","a24","a25","a26","a27","a28","a29","a30","a31", \
  "a32","a33","a34","a35","a36","a37","a38","a39","a40","a41","a42","a43","a44","a45","a46","a47", \
  "a48","a49","a50","a51","a52","a53","a54","a55","a56","a57","a58","a59","a60","a61","a62","a63", \
  "a64","a65","a66","a67","a68","a69","a70","a71","a72","a73","a74","a75","a76","a77","a78","a79", \
  "a80","a81","a82","a83","a84","a85","a86","a87","a88","a89","a90","a91","a92","a93","a94","a95", \
  "a96","a97","a98","a99","a100","a101","a102","a103","a104","a105","a106","a107","a108","a109","a110","a111", \
  "a112","a113","a114","a115","a116","a117","a118","a119","a120","a121","a122","a123","a124","a125","a126","a127"

// ---------------- pack weights into MFMA B-fragment layout (with gate pre-scaling) ----
__global__ void pack_w_kernel(const float* __restrict__ W, int rows, int k_base,
                              int n_tiles, int k_tiles, int mode,
                              unsigned short* __restrict__ dst) {
  int gid = blockIdx.x * blockDim.x + threadIdx.x;
  int total = n_tiles * k_tiles * 64;
  if (gid >= total) return;
  int lane = gid & 63;
  int fi = gid >> 6;
  int kt = fi % k_tiles;
  int nt = fi / k_tiles;
  int n = nt * 16 + (lane & 15);
  int g, col; float s;
  if (mode == 0)      { g = n >> 8;            col = n & 255; s = (g == 1) ? S_C : S_RZ; }
  else if (mode == 1) { g = (n < 256) ? 0 : 2; col = n & 255; s = S_RZ; }
  else                { g = 1;                 col = n;       s = S_C; }
  int k0 = k_base + kt * 32 + ((lane >> 4) << 3);
  const float* src = W + ((size_t)g * rows + k0) * 256 + col;
  unsigned short v[8];
#pragma unroll
  for (int j = 0; j < 8; ++j) v[j] = f2bf(src[(size_t)j * 256] * s);
  uint4 o;
  o.x = v[0] | ((unsigned)v[1] << 16);
  o.y = v[2] | ((unsigned)v[3] << 16);
  o.z = v[4] | ((unsigned)v[5] << 16);
  o.w = v[6] | ((unsigned)v[7] << 16);
  ((uint4*)dst)[gid] = o;
}

static __device__ __forceinline__ bf16x8 cvt8(float4 f0, float4 f1) {
  uint4 o;
  o.x = f2bf(f0.x) | ((unsigned)f2bf(f0.y) << 16);
  o.y = f2bf(f0.z) | ((unsigned)f2bf(f0.w) << 16);
  o.z = f2bf(f1.x) | ((unsigned)f2bf(f1.y) << 16);
  o.w = f2bf(f1.z) | ((unsigned)f2bf(f1.w) << 16);
  FragU f; f.u = o; return f.v;
}

// ---------------- Xg GEMM (chunked): writes C-fragment tile layout --------------------
template<int LAYER>
__global__ __launch_bounds__(256)
void gemm_xg_kernel(const float* __restrict__ x,
                    const unsigned short* __restrict__ fs0,
                    const unsigned short* __restrict__ bs0,
                    const unsigned short* __restrict__ Bp,
                    const float* __restrict__ bias_fw,
                    const float* __restrict__ bias_bw,
                    f32x4* __restrict__ Xg, int t0, int chunkT)
{
  constexpr int KT = (LAYER == 0) ? 8 : 16;
  int dir = blockIdx.z;
  int lane = threadIdx.x & 63;
  int w = threadIdx.x >> 6;
  int ww = w >> 1, wc = w & 1;
  int mt0 = blockIdx.x * 8 + ww * 4;
  int nt0 = blockIdx.y * 8 + wc * 4;
  const uint4* B = (const uint4*)Bp + (size_t)dir * 48 * KT * 64;
  const int arow = lane & 15;
  const int k0b = ((lane >> 4) << 3);

  f32x4 acc[4][4] = {};
#pragma unroll
  for (int kt = 0; kt < KT; ++kt) {
    int k0 = kt * 32 + k0b;
    bf16x8 a[4], b[4];
#pragma unroll
    for (int i = 0; i < 4; ++i) {
      int grow = t0 * 64 + (mt0 + i) * 16 + arow;
      if (LAYER == 0) {
        int gr = dir ? revrow(grow) : grow;
        const float4* s = (const float4*)(x + (size_t)gr * 256 + k0);
        a[i] = cvt8(s[0], s[1]);
      } else {
        const unsigned short* base; int r2 = grow, kk = k0;
        if (k0 < 256) { base = dir ? bs0 : fs0; }
        else          { base = dir ? fs0 : bs0; r2 = revrow(grow); kk = k0 - 256; }
        a[i] = *(const bf16x8*)(base + (size_t)r2 * 256 + kk);
      }
    }
#pragma unroll
    for (int j = 0; j < 4; ++j) b[j] = ld_frag(B + ((size_t)(nt0 + j) * KT + kt) * 64 + lane);
#pragma unroll
    for (int i = 0; i < 4; ++i)
#pragma unroll
      for (int j = 0; j < 4; ++j)
        acc[i][j] = __builtin_amdgcn_mfma_f32_16x16x32_bf16(a[i], b[j], acc[i][j], 0, 0, 0);
  }

  const float* bias = dir ? bias_bw : bias_fw;
  f32x4* C = Xg + (size_t)dir * (chunkT * 4) * 48 * 64;
#pragma unroll
  for (int j = 0; j < 4; ++j) {
    int ct = nt0 + j;
    int col = ct * 16 + (lane & 15);
    int g = col >> 8, cc = col & 255;
    float bv = ((g == 1) ? S_C : S_RZ) * bias[g * 256 + cc];
#pragma unroll
    for (int i = 0; i < 4; ++i) {
      int rt = blockIdx.x * 8 + ww * 4 + i;
      f32x4 v = acc[i][j];
      v[0] += bv; v[1] += bv; v[2] += bv; v[3] += bv;
      C[((size_t)rt * 48 + ct) * 64 + lane] = v;
    }
  }
}

// ---------------- persistent recurrent GRU kernel (one layer, both dirs, chunked) -----
// grid (4, 2), 512 threads = 8 waves. Whrz in physical a0..a127; Whc in LDS.
// z epilogue deferred past barrier 1; 4-chain phase B; cvt_pk bf16 conversions.
template<int LAYER>
__global__ __launch_bounds__(512) __attribute__((amdgpu_waves_per_eu(2, 2)))
void gru_kernel(const f32x4* __restrict__ Xg,
                const uint4* __restrict__ whrz_fw, const uint4* __restrict__ whrz_bw, // [32][8][64]
                const uint4* __restrict__ whc_fw,  const uint4* __restrict__ whc_bw,  // [16][8][64]
                unsigned short* __restrict__ sfw_bf, unsigned short* __restrict__ sbw_bf,
                float* __restrict__ out,
                float* __restrict__ hstate, float* __restrict__ dout_h,
                int t0, int chunkT)
{
  const int dir = blockIdx.y;
  const int bx = blockIdx.x;
  const int row0 = bx * 16;
  const int tid = threadIdx.x;
  const int lane = tid & 63;
  const int w = tid >> 6;               // 0..7

  __shared__ __align__(16) unsigned short h_bf[16 * 256];   // swizzled bf16 h       (8 KB)
  __shared__ __align__(16) unsigned short rh_bf[16 * 256];  // swizzled bf16 r*h     (8 KB)
  __shared__ __align__(16) uint4 wc_lds[16 * 8 * 64];       // Whc B-fragments     (128 KB)

  const uint4* whrzp = dir ? whrz_bw : whrz_fw;
  const uint4* whcp  = dir ? whc_bw  : whc_fw;

  for (int i = tid; i < 16 * 8 * 64; i += 512) wc_lds[i] = whcp[i];

  LOADF(0, 0, 1, 2, 3);     LOADF(1, 4, 5, 6, 7);     LOADF(2, 8, 9, 10, 11);   LOADF(3, 12, 13, 14, 15);
  LOADF(4, 16, 17, 18, 19); LOADF(5, 20, 21, 22, 23); LOADF(6, 24, 25, 26, 27); LOADF(7, 28, 29, 30, 31);
  LOADF(8, 32, 33, 34, 35); LOADF(9, 36, 37, 38, 39); LOADF(10, 40, 41, 42, 43); LOADF(11, 44, 45, 46, 47);
  LOADF(12, 48, 49, 50, 51); LOADF(13, 52, 53, 54, 55); LOADF(14, 56, 57, 58, 59); LOADF(15, 60, 61, 62, 63);
  LOADF(16, 64, 65, 66, 67); LOADF(17, 68, 69, 70, 71); LOADF(18, 72, 73, 74, 75); LOADF(19, 76, 77, 78, 79);
  LOADF(20, 80, 81, 82, 83); LOADF(21, 84, 85, 86, 87); LOADF(22, 88, 89, 90, 91); LOADF(23, 92, 93, 94, 95);
  LOADF(24, 96, 97, 98, 99); LOADF(25, 100, 101, 102, 103); LOADF(26, 104, 105, 106, 107); LOADF(27, 108, 109, 110, 111);
  LOADF(28, 112, 113, 114, 115); LOADF(29, 116, 117, 118, 119); LOADF(30, 120, 121, 122, 123); LOADF(31, 124, 125, 126, 127);

  const int ccol = lane & 15;
  const int crow = ((lane >> 4) << 2);     // 0,4,8,12

  float* hst = hstate + (size_t)(dir * 4 + bx) * 4096;
  for (int i = tid; i < 16 * 256; i += 512) {
    float v = (t0 == 0) ? 0.0f : hst[i];
    int rr = i >> 8, cc = i & 255;
    int cb = cc * 2;
    int byt = rr * 512 + (((cb & ~15) ^ ((rr & 7) << 4)) | (cb & 15));
    *(unsigned short*)((char*)h_bf + byt) = f2bf(v);
  }
  float hreg[2][4];
#pragma unroll
  for (int j = 0; j < 2; ++j)
#pragma unroll
    for (int r = 0; r < 4; ++r) {
      int rr = crow + r, c = (w * 2 + j) * 16 + ccol;
      hreg[j][r] = (t0 == 0) ? 0.0f : hst[rr * 256 + c];
    }
  __syncthreads();

  const int ctR0 = w * 2, ctR1 = w * 2 + 1;
  const int ctZ0 = 32 + w * 2, ctZ1 = 33 + w * 2;
  const int ctB0c = 16 + w * 2, ctB1c = 17 + w * 2;
  const f32x4* XgD = Xg + (size_t)dir * (chunkT * 4) * 48 * 64;
  unsigned short* sp_bf = dir ? sbw_bf : sfw_bf;
  const int coff = dir ? 256 : 0;
  const int ardbase = (lane & 15) * 512;
  const int arxor = ((lane & 7) << 4);
  const int afc = ((lane >> 4) << 4);

#define AFRAG(KT) (*(const bf16x8*)((const char*)h_bf + (ardbase + ((KT * 64 + afc) ^ arxor))))
#define RFRAG(KT) (*(const bf16x8*)((const char*)rh_bf + (ardbase + ((KT * 64 + afc) ^ arxor))))
#define SWZ(rr, cb) ((rr) * 512 + ((((cb) & ~15) ^ (((rr) & 7) << 4)) | ((cb) & 15)))

  // prologue: load step-0 Xg into the double-buffer registers
  f32x4 xa0, xa1, xa2, xa3, xb0, xb1;
  {
    size_t rtb0 = ((size_t)(0 * 4 + bx) * 48) * 64 + lane;
    xa0 = XgD[rtb0 + (size_t)ctR0 * 64];
    xa1 = XgD[rtb0 + (size_t)ctR1 * 64];
    xa2 = XgD[rtb0 + (size_t)ctZ0 * 64];
    xa3 = XgD[rtb0 + (size_t)ctZ1 * 64];
    xb0 = XgD[rtb0 + (size_t)ctB0c * 64];
    xb1 = XgD[rtb0 + (size_t)ctB1c * 64];
  }

#pragma unroll 1
  for (int t = t0; t < t0 + chunkT; ++t) {
    const int tloc = t - t0;

    // ---------- phase A: rz = h @ Whrz, weights from pinned AGPRs ----------
    f32x4 accA0 = {}, accA1 = {}, accA2 = {}, accA3 = {};
    {
      bf16x8 af;
      af = AFRAG(0);
      MFMA_A1(accA0, af, 0, 3);   MFMA_A1(accA1, af, 32, 35);
      MFMA_A1(accA2, af, 64, 67); MFMA_A1(accA3, af, 96, 99);
      af = AFRAG(1);
      MFMA_A(accA0, af, 4, 7);    MFMA_A(accA1, af, 36, 39);
      MFMA_A(accA2, af, 68, 71);  MFMA_A(accA3, af, 100, 103);
      af = AFRAG(2);
      MFMA_A(accA0, af, 8, 11);   MFMA_A(accA1, af, 40, 43);
      MFMA_A(accA2, af, 72, 75);  MFMA_A(accA3, af, 104, 107);
      af = AFRAG(3);
      MFMA_A(accA0, af, 12, 15);  MFMA_A(accA1, af, 44, 47);
      MFMA_A(accA2, af, 76, 79);  MFMA_A(accA3, af, 108, 111);
      af = AFRAG(4);
      MFMA_A(accA0, af, 16, 19);  MFMA_A(accA1, af, 48, 51);
      MFMA_A(accA2, af, 80, 83);  MFMA_A(accA3, af, 112, 115);
      af = AFRAG(5);
      MFMA_A(accA0, af, 20, 23);  MFMA_A(accA1, af, 52, 55);
      MFMA_A(accA2, af, 84, 87);  MFMA_A(accA3, af, 116, 119);
      af = AFRAG(6);
      MFMA_A(accA0, af, 24, 27);  MFMA_A(accA1, af, 56, 59);
      MFMA_A(accA2, af, 88, 91);  MFMA_A(accA3, af, 120, 123);
      af = AFRAG(7);
      MFMA_A(accA0, af, 28, 31);  MFMA_A(accA1, af, 60, 63);
      MFMA_A(accA2, af, 92, 95);  MFMA_A(accA3, af, 124, 127);
    }
    ACCFENCE2(accA0, accA1);

    // epilogue A (r-gates only): rh -> LDS via packed bf16 pairs
#pragma unroll
    for (int j = 0; j < 2; ++j) {
      f32x4 ac = j ? accA1 : accA0;
      f32x4 xv = j ? xa1 : xa0;
      int cb = ((w * 2 + j) * 16 + ccol) * 2;
      float rh[4];
#pragma unroll
      for (int r = 0; r < 4; ++r) {
        float v = ac[r] + xv[r];
        float gate = __builtin_amdgcn_rcpf(1.0f + __builtin_amdgcn_exp2f(v)); // sigmoid(r)
        rh[r] = gate * hreg[j][r];
      }
      unsigned p01 = cvt_pk_bf16(rh[0], rh[1]);
      unsigned p23 = cvt_pk_bf16(rh[2], rh[3]);
      *(unsigned short*)((char*)rh_bf + SWZ(crow + 0, cb)) = (unsigned short)p01;
      *(unsigned short*)((char*)rh_bf + SWZ(crow + 1, cb)) = (unsigned short)(p01 >> 16);
      *(unsigned short*)((char*)rh_bf + SWZ(crow + 2, cb)) = (unsigned short)p23;
      *(unsigned short*)((char*)rh_bf + SWZ(crow + 3, cb)) = (unsigned short)(p23 >> 16);
    }
    asm volatile("s_waitcnt lgkmcnt(0)" ::: "memory", ACLB);
    __builtin_amdgcn_s_barrier();

    // ---------- phase B ----------
    // deferred z epilogue (overlaps phase-B LDS reads)
    ACCFENCE2(accA2, accA3);
    float zreg[2][4];
#pragma unroll
    for (int j = 0; j < 2; ++j) {
      f32x4 ac = j ? accA3 : accA2;
      f32x4 xv = j ? xa3 : xa2;
#pragma unroll
      for (int r = 0; r < 4; ++r) {
        float v = ac[r] + xv[r];
        zreg[j][r] = __builtin_amdgcn_rcpf(1.0f + __builtin_amdgcn_exp2f(v)); // sigmoid(z)
      }
    }

    // cand = tanh-form((r*h) @ Whc + x-part) — 4 kt-split chains (no dep stalls)
    f32x4 accB0a = {}, accB0b = {}, accB1a = {}, accB1b = {};
#pragma unroll
    for (int kt = 0; kt < 4; ++kt) {
      bf16x8 a = RFRAG(kt);
      bf16x8 b0 = *(const bf16x8*)&wc_lds[((size_t)(w * 2 + 0) * 8 + kt) * 64 + lane];
      bf16x8 b1 = *(const bf16x8*)&wc_lds[((size_t)(w * 2 + 1) * 8 + kt) * 64 + lane];
      if (kt == 0) { MFMA_V1(accB0a, a, b0); MFMA_V1(accB1a, a, b1); }
      else         { MFMA_V(accB0a, a, b0);  MFMA_V(accB1a, a, b1); }
    }
#pragma unroll
    for (int kt = 4; kt < 8; ++kt) {
      bf16x8 a = RFRAG(kt);
      bf16x8 b0 = *(const bf16x8*)&wc_lds[((size_t)(w * 2 + 0) * 8 + kt) * 64 + lane];
      bf16x8 b1 = *(const bf16x8*)&wc_lds[((size_t)(w * 2 + 1) * 8 + kt) * 64 + lane];
      if (kt == 4) { MFMA_V1(accB0b, a, b0); MFMA_V1(accB1b, a, b1); }
      else         { MFMA_V(accB0b, a, b0);  MFMA_V(accB1b, a, b1); }
    }
    // capture current-step cand x-parts, then prefetch next step's Xg
    f32x4 cb0 = xb0, cb1 = xb1;
    {
      int tn = (tloc + 1 < chunkT) ? tloc + 1 : tloc;
      size_t rtn = ((size_t)(tn * 4 + bx) * 48) * 64 + lane;
      xa0 = XgD[rtn + (size_t)ctR0 * 64];
      xa1 = XgD[rtn + (size_t)ctR1 * 64];
      xa2 = XgD[rtn + (size_t)ctZ0 * 64];
      xa3 = XgD[rtn + (size_t)ctZ1 * 64];
      xb0 = XgD[rtn + (size_t)ctB0c * 64];
      xb1 = XgD[rtn + (size_t)ctB1c * 64];
    }
    ACCFENCE4(accB0a, accB0b, accB1a, accB1b);
    f32x4 accB0 = accB0a + accB0b;
    f32x4 accB1 = accB1a + accB1b;

    int gbase = (LAYER == 1 && dir) ? ((T_STEPS - 1 - t) * 64 + row0) : (t * 64 + row0);
#pragma unroll
    for (int j = 0; j < 2; ++j) {
      f32x4 ac = j ? accB1 : accB0;
      f32x4 xv = j ? cb1 : cb0;
      int c2 = (w * 2 + j) * 16 + ccol;
      int cb = c2 * 2;
      float hn[4];
#pragma unroll
      for (int r = 0; r < 4; ++r) {
        float v = ac[r] + xv[r];
        float cand = __builtin_amdgcn_rcpf(1.0f + __builtin_amdgcn_exp2f(v)) * 2.0f - 1.0f;
        hn[r] = cand + zreg[j][r] * (hreg[j][r] - cand);
        hreg[j][r] = hn[r];
      }
      unsigned p01 = cvt_pk_bf16(hn[0], hn[1]);
      unsigned p23 = cvt_pk_bf16(hn[2], hn[3]);
      *(unsigned short*)((char*)h_bf + SWZ(crow + 0, cb)) = (unsigned short)p01;
      *(unsigned short*)((char*)h_bf + SWZ(crow + 1, cb)) = (unsigned short)(p01 >> 16);
      *(unsigned short*)((char*)h_bf + SWZ(crow + 2, cb)) = (unsigned short)p23;
      *(unsigned short*)((char*)h_bf + SWZ(crow + 3, cb)) = (unsigned short)(p23 >> 16);
      if (LAYER == 0) {
        sp_bf[(size_t)(gbase + crow + 0) * 256 + c2] = (unsigned short)p01;
        sp_bf[(size_t)(gbase + crow + 1) * 256 + c2] = (unsigned short)(p01 >> 16);
        sp_bf[(size_t)(gbase + crow + 2) * 256 + c2] = (unsigned short)p23;
        sp_bf[(size_t)(gbase + crow + 3) * 256 + c2] = (unsigned short)(p23 >> 16);
      } else {
#pragma unroll
        for (int r = 0; r < 4; ++r)
          out[(size_t)(gbase + crow + r) * 512 + coff + c2] = hn[r];
      }
    }
    asm volatile("s_waitcnt lgkmcnt(0)" ::: "memory", ACLB);
    __builtin_amdgcn_s_barrier();
  }

  // persist h; on last chunk also write fh/bh
#pragma unroll
  for (int j = 0; j < 2; ++j)
#pragma unroll
    for (int r = 0; r < 4; ++r) {
      int rr = crow + r, c = (w * 2 + j) * 16 + ccol;
      hst[rr * 256 + c] = hreg[j][r];
      if (t0 + chunkT == T_STEPS) {
        float* dst = dout_h + (dir ? 32768 : 0) + (size_t)LAYER * 16384;
        dst[(size_t)(row0 + rr) * 256 + c] = hreg[j][r];
      }
    }
}

__global__ void diag_kernel(float* out, float v) { out[0] = v; }

// --------------------------------------------------------------------------------------
extern "C" void kernel_launch(void* const* d_in, const int* in_sizes, int n_in,
                              void* d_out, int out_size, void* d_ws, size_t ws_size,
                              hipStream_t stream) {
  const float* x     = (const float*)d_in[0];
  const float* fw_W0 = (const float*)d_in[2];
  const float* fw_b0 = (const float*)d_in[3];
  const float* fw_W1 = (const float*)d_in[4];
  const float* fw_b1 = (const float*)d_in[5];
  const float* bw_W0 = (const float*)d_in[6];
  const float* bw_b0 = (const float*)d_in[7];
  const float* bw_W1 = (const float*)d_in[8];
  const float* bw_b1 = (const float*)d_in[9];

  char* ws = (char*)d_ws;
  size_t off = 0;
  auto alloc = [&](size_t bytes) -> char* {
    char* p = ws + off; off += (bytes + 255) & ~(size_t)255; return p;
  };
  unsigned short* Wx0p  = (unsigned short*)alloc(2ull * 48 * 8 * 64 * 8 * 2);
  unsigned short* Wx1p  = (unsigned short*)alloc(2ull * 48 * 16 * 64 * 8 * 2);
  unsigned short* Whrz0 = (unsigned short*)alloc(2ull * 32 * 8 * 64 * 8 * 2);
  unsigned short* Whc0  = (unsigned short*)alloc(2ull * 16 * 8 * 64 * 8 * 2);
  unsigned short* Whrz1 = (unsigned short*)alloc(2ull * 32 * 8 * 64 * 8 * 2);
  unsigned short* Whc1  = (unsigned short*)alloc(2ull * 16 * 8 * 64 * 8 * 2);
  unsigned short* fs0   = (unsigned short*)alloc((size_t)TB * 256 * 2);
  unsigned short* bs0   = (unsigned short*)alloc((size_t)TB * 256 * 2);
  float* hstate         = (float*)alloc(2ull * 4 * 16 * 256 * 4);

  int chunkT = 0;
  for (int ct = 128; ct >= 8; ct >>= 1) {
    if (off + (size_t)ct * 2 * 64 * 768 * 4 <= ws_size) { chunkT = ct; break; }
  }
  float* out = (float*)d_out;
  if (chunkT == 0) {
    diag_kernel<<<1, 1, 0, stream>>>(out, 12345.0f);
    return;
  }
  f32x4* Xg = (f32x4*)alloc((size_t)chunkT * 2 * 64 * 768 * 4);
  float* dout_h = out + (size_t)TB * 512;

  auto packw = [&](const float* W, int rows, int kb, int ntl, int ktl, int mode, unsigned short* dst) {
    int total = ntl * ktl * 64;
    pack_w_kernel<<<(total + 255) / 256, 256, 0, stream>>>(W, rows, kb, ntl, ktl, mode, dst);
  };
  packw(fw_W0, 512, 0,   48, 8,  0, Wx0p);
  packw(bw_W0, 512, 0,   48, 8,  0, Wx0p + 48 * 8 * 64 * 8);
  packw(fw_W1, 768, 0,   48, 16, 0, Wx1p);
  packw(bw_W1, 768, 0,   48, 16, 0, Wx1p + 48 * 16 * 64 * 8);
  packw(fw_W0, 512, 256, 32, 8,  1, Whrz0);
  packw(bw_W0, 512, 256, 32, 8,  1, Whrz0 + 32 * 8 * 64 * 8);
  packw(fw_W0, 512, 256, 16, 8,  2, Whc0);
  packw(bw_W0, 512, 256, 16, 8,  2, Whc0 + 16 * 8 * 64 * 8);
  packw(fw_W1, 768, 512, 32, 8,  1, Whrz1);
  packw(bw_W1, 768, 512, 32, 8,  1, Whrz1 + 32 * 8 * 64 * 8);
  packw(fw_W1, 768, 512, 16, 8,  2, Whc1);
  packw(bw_W1, 768, 512, 16, 8,  2, Whc1 + 16 * 8 * 64 * 8);

  dim3 rgrid(4, 2);
  // layer 0
  for (int t0 = 0; t0 < T_STEPS; t0 += chunkT) {
    dim3 ggrid(chunkT / 2, 6, 2);
    gemm_xg_kernel<0><<<ggrid, 256, 0, stream>>>(x, nullptr, nullptr, Wx0p, fw_b0, bw_b0, Xg, t0, chunkT);
    gru_kernel<0><<<rgrid, 512, 0, stream>>>(Xg,
        (const uint4*)Whrz0, (const uint4*)(Whrz0 + 32 * 8 * 64 * 8),
        (const uint4*)Whc0,  (const uint4*)(Whc0 + 16 * 8 * 64 * 8),
        fs0, bs0, nullptr, hstate, dout_h, t0, chunkT);
  }
  // layer 1
  for (int t0 = 0; t0 < T_STEPS; t0 += chunkT) {
    dim3 ggrid(chunkT / 2, 6, 2);
    gemm_xg_kernel<1><<<ggrid, 256, 0, stream>>>(nullptr, fs0, bs0, Wx1p, fw_b1, bw_b1, Xg, t0, chunkT);
    gru_kernel<1><<<rgrid, 512, 0, stream>>>(Xg,
        (const uint4*)Whrz1, (const uint4*)(Whrz1 + 32 * 8 * 64 * 8),
        (const uint4*)Whc1,  (const uint4*)(Whc1 + 16 * 8 * 64 * 8),
        nullptr, nullptr, out, hstate, dout_h, t0, chunkT);
  }
}

// Round 11
// 2505.112 us; speedup vs baseline: 1.7050x; 1.0179x over previous
//
#include <hip/hip_runtime.h>
#include <hip/hip_bf16.h>

#define T_STEPS 512
#define BATCH 64
#define TB (T_STEPS * BATCH)   // 32768

typedef short bf16x8 __attribute__((ext_vector_type(8)));
typedef float f32x4 __attribute__((ext_vector_type(4)));

union FragU { uint4 u; bf16x8 v; };

static __device__ __forceinline__ bf16x8 ld_frag(const uint4* p) {
  FragU f; f.u = *p; return f.v;
}

static __device__ __forceinline__ unsigned short f2bf(float f) {
  unsigned u = __float_as_uint(f);
  return (unsigned short)((u + 0x7FFFu + ((u >> 16) & 1u)) >> 16);
}

// packed f32->bf16 (RNE), 1 inst per pair
static __device__ __forceinline__ unsigned cvt_pk_bf16(float lo, float hi) {
  unsigned r;
  asm("v_cvt_pk_bf16_f32 %0, %1, %2" : "=v"(r) : "v"(lo), "v"(hi));
  return r;
}

static __device__ __forceinline__ int revrow(int r) {
  int t = r >> 6, b = r & 63;
  return ((T_STEPS - 1 - t) << 6) | b;
}

#define S_RZ  (-1.4426950408889634f)   /* -log2(e)   : sigmoid(p)=1/(1+2^(S_RZ*p)) */
#define S_C   (-2.8853900817779268f)   /* -2*log2(e) : tanh(p)=2/(1+2^(S_C*p))-1   */

// ---- explicit named-AGPR weight residency (round-8/9/10-validated) -------------------
#define AWR(N, x) asm volatile("v_accvgpr_write_b32 a" #N ", %0" :: "v"(x) : "a" #N)
#define LOADF(F, A0, A1, A2, A3) do { \
    const int c_ = (F) >> 3, kt_ = (F) & 7; \
    const int nt_ = (c_ < 2) ? (w * 2 + c_) : (14 + w * 2 + c_); \
    uint4 t = whrzp[((size_t)nt_ * 8 + kt_) * 64 + lane]; \
    AWR(A0, t.x); AWR(A1, t.y); AWR(A2, t.z); AWR(A3, t.w); } while (0)

#define MFMA_A(acc, va, B0, B3) \
  asm volatile("v_mfma_f32_16x16x32_bf16 %0, %1, a[" #B0 ":" #B3 "], %0" \
               : "+v"(acc) : "v"(va))
// first MFMA of a chain: C-in = long-lived zero quad (no v_mov zero-init per step)
#define MFMA_AZ(acc, va, B0, B3, zq) \
  asm volatile("v_mfma_f32_16x16x32_bf16 %0, %1, a[" #B0 ":" #B3 "], %2" \
               : "=&v"(acc) : "v"(va), "v"(zq))
#define MFMA_V(acc, va, vb) \
  asm volatile("v_mfma_f32_16x16x32_bf16 %0, %1, %2, %0" \
               : "+v"(acc) : "v"(va), "v"(vb))
#define MFMA_VZ(acc, va, vb, zq) \
  asm volatile("v_mfma_f32_16x16x32_bf16 %0, %1, %2, %3" \
               : "=&v"(acc) : "v"(va), "v"(vb), "v"(zq))
// fences before VALU reads of MFMA results (16 wait-state slots, shared per group)
#define ACCFENCE2(a, b) asm volatile("s_nop 7\n\ts_nop 7" : "+v"(a), "+v"(b))
#define ACCFENCE4(a, b, c, d) \
  asm volatile("s_nop 7\n\ts_nop 7" : "+v"(a), "+v"(b), "+v"(c), "+v"(d))

#define ACLB \
  "a0","a1","a2","a3","a4","a5","a6","a7","a8","a9","a10","a11","a12","a13","a14","a15", \
  "a16","a17","a18","a19","a20","a21","a22","a23","a24","a25","a26","a27","a28","a29","a30","a31", \
  "a32","a33","a34","a35","a36","a37","a38","a39","a40","a41","a42","a43","a44","a45","a46","a47", \
  "a48","a49","a50","a51","a52","a53","a54","a55","a56","a57","a58","a59","a60","a61","a62","a63", \
  "a64","a65","a66","a67","a68","a69","a70","a71","a72","a73","a74","a75","a76","a77","a78","a79", \
  "a80","a81","a82","a83","a84","a85","a86","a87","a88","a89","a90","a91","a92","a93","a94","a95", \
  "a96","a97","a98","a99","a100","a101","a102","a103","a104","a105","a106","a107","a108","a109","a110","a111", \
  "a112","a113","a114","a115","a116","a117","a118","a119","a120","a121","a122","a123","a124","a125","a126","a127"

// ---------------- pack weights into MFMA B-fragment layout (with gate pre-scaling) ----
__global__ void pack_w_kernel(const float* __restrict__ W, int rows, int k_base,
                              int n_tiles, int k_tiles, int mode,
                              unsigned short* __restrict__ dst) {
  int gid = blockIdx.x * blockDim.x + threadIdx.x;
  int total = n_tiles * k_tiles * 64;
  if (gid >= total) return;
  int lane = gid & 63;
  int fi = gid >> 6;
  int kt = fi % k_tiles;
  int nt = fi / k_tiles;
  int n = nt * 16 + (lane & 15);
  int g, col; float s;
  if (mode == 0)      { g = n >> 8;            col = n & 255; s = (g == 1) ? S_C : S_RZ; }
  else if (mode == 1) { g = (n < 256) ? 0 : 2; col = n & 255; s = S_RZ; }
  else                { g = 1;                 col = n;       s = S_C; }
  int k0 = k_base + kt * 32 + ((lane >> 4) << 3);
  const float* src = W + ((size_t)g * rows + k0) * 256 + col;
  unsigned short v[8];
#pragma unroll
  for (int j = 0; j < 8; ++j) v[j] = f2bf(src[(size_t)j * 256] * s);
  uint4 o;
  o.x = v[0] | ((unsigned)v[1] << 16);
  o.y = v[2] | ((unsigned)v[3] << 16);
  o.z = v[4] | ((unsigned)v[5] << 16);
  o.w = v[6] | ((unsigned)v[7] << 16);
  ((uint4*)dst)[gid] = o;
}

static __device__ __forceinline__ bf16x8 cvt8(float4 f0, float4 f1) {
  uint4 o;
  o.x = f2bf(f0.x) | ((unsigned)f2bf(f0.y) << 16);
  o.y = f2bf(f0.z) | ((unsigned)f2bf(f0.w) << 16);
  o.z = f2bf(f1.x) | ((unsigned)f2bf(f1.y) << 16);
  o.w = f2bf(f1.z) | ((unsigned)f2bf(f1.w) << 16);
  FragU f; f.u = o; return f.v;
}

// ---------------- Xg GEMM (chunked): writes C-fragment tile layout --------------------
template<int LAYER>
__global__ __launch_bounds__(256)
void gemm_xg_kernel(const float* __restrict__ x,
                    const unsigned short* __restrict__ fs0,
                    const unsigned short* __restrict__ bs0,
                    const unsigned short* __restrict__ Bp,
                    const float* __restrict__ bias_fw,
                    const float* __restrict__ bias_bw,
                    f32x4* __restrict__ Xg, int t0, int chunkT)
{
  constexpr int KT = (LAYER == 0) ? 8 : 16;
  int dir = blockIdx.z;
  int lane = threadIdx.x & 63;
  int w = threadIdx.x >> 6;
  int ww = w >> 1, wc = w & 1;
  int mt0 = blockIdx.x * 8 + ww * 4;
  int nt0 = blockIdx.y * 8 + wc * 4;
  const uint4* B = (const uint4*)Bp + (size_t)dir * 48 * KT * 64;
  const int arow = lane & 15;
  const int k0b = ((lane >> 4) << 3);

  f32x4 acc[4][4] = {};
#pragma unroll
  for (int kt = 0; kt < KT; ++kt) {
    int k0 = kt * 32 + k0b;
    bf16x8 a[4], b[4];
#pragma unroll
    for (int i = 0; i < 4; ++i) {
      int grow = t0 * 64 + (mt0 + i) * 16 + arow;
      if (LAYER == 0) {
        int gr = dir ? revrow(grow) : grow;
        const float4* s = (const float4*)(x + (size_t)gr * 256 + k0);
        a[i] = cvt8(s[0], s[1]);
      } else {
        const unsigned short* base; int r2 = grow, kk = k0;
        if (k0 < 256) { base = dir ? bs0 : fs0; }
        else          { base = dir ? fs0 : bs0; r2 = revrow(grow); kk = k0 - 256; }
        a[i] = *(const bf16x8*)(base + (size_t)r2 * 256 + kk);
      }
    }
#pragma unroll
    for (int j = 0; j < 4; ++j) b[j] = ld_frag(B + ((size_t)(nt0 + j) * KT + kt) * 64 + lane);
#pragma unroll
    for (int i = 0; i < 4; ++i)
#pragma unroll
      for (int j = 0; j < 4; ++j)
        acc[i][j] = __builtin_amdgcn_mfma_f32_16x16x32_bf16(a[i], b[j], acc[i][j], 0, 0, 0);
  }

  const float* bias = dir ? bias_bw : bias_fw;
  f32x4* C = Xg + (size_t)dir * (chunkT * 4) * 48 * 64;
#pragma unroll
  for (int j = 0; j < 4; ++j) {
    int ct = nt0 + j;
    int col = ct * 16 + (lane & 15);
    int g = col >> 8, cc = col & 255;
    float bv = ((g == 1) ? S_C : S_RZ) * bias[g * 256 + cc];
#pragma unroll
    for (int i = 0; i < 4; ++i) {
      int rt = blockIdx.x * 8 + ww * 4 + i;
      f32x4 v = acc[i][j];
      v[0] += bv; v[1] += bv; v[2] += bv; v[3] += bv;
      C[((size_t)rt * 48 + ct) * 64 + lane] = v;
    }
  }
}

// ---------------- persistent recurrent GRU kernel (one layer, both dirs, chunked) -----
// grid (4, 2), 512 threads = 8 waves. Whrz in physical a0..a127; Whc in LDS.
// Hoisted LDS addresses, strided global pointers, zero-quad MFMA C-in.
template<int LAYER>
__global__ __launch_bounds__(512) __attribute__((amdgpu_waves_per_eu(2, 2)))
void gru_kernel(const f32x4* __restrict__ Xg,
                const uint4* __restrict__ whrz_fw, const uint4* __restrict__ whrz_bw, // [32][8][64]
                const uint4* __restrict__ whc_fw,  const uint4* __restrict__ whc_bw,  // [16][8][64]
                unsigned short* __restrict__ sfw_bf, unsigned short* __restrict__ sbw_bf,
                float* __restrict__ out,
                float* __restrict__ hstate, float* __restrict__ dout_h,
                int t0, int chunkT)
{
  const int dir = blockIdx.y;
  const int bx = blockIdx.x;
  const int row0 = bx * 16;
  const int tid = threadIdx.x;
  const int lane = tid & 63;
  const int w = tid >> 6;               // 0..7

  // hx: [rh bf16 swizzled 8KB][h bf16 swizzled 8KB] — h = rh_addr + 8192 (offset imm)
  __shared__ __align__(16) unsigned short hx[2 * 16 * 256];
  __shared__ __align__(16) uint4 wc_lds[16 * 8 * 64];       // Whc B-fragments (128 KB)

  const uint4* whrzp = dir ? whrz_bw : whrz_fw;
  const uint4* whcp  = dir ? whc_bw  : whc_fw;

  for (int i = tid; i < 16 * 8 * 64; i += 512) wc_lds[i] = whcp[i];

  LOADF(0, 0, 1, 2, 3);     LOADF(1, 4, 5, 6, 7);     LOADF(2, 8, 9, 10, 11);   LOADF(3, 12, 13, 14, 15);
  LOADF(4, 16, 17, 18, 19); LOADF(5, 20, 21, 22, 23); LOADF(6, 24, 25, 26, 27); LOADF(7, 28, 29, 30, 31);
  LOADF(8, 32, 33, 34, 35); LOADF(9, 36, 37, 38, 39); LOADF(10, 40, 41, 42, 43); LOADF(11, 44, 45, 46, 47);
  LOADF(12, 48, 49, 50, 51); LOADF(13, 52, 53, 54, 55); LOADF(14, 56, 57, 58, 59); LOADF(15, 60, 61, 62, 63);
  LOADF(16, 64, 65, 66, 67); LOADF(17, 68, 69, 70, 71); LOADF(18, 72, 73, 74, 75); LOADF(19, 76, 77, 78, 79);
  LOADF(20, 80, 81, 82, 83); LOADF(21, 84, 85, 86, 87); LOADF(22, 88, 89, 90, 91); LOADF(23, 92, 93, 94, 95);
  LOADF(24, 96, 97, 98, 99); LOADF(25, 100, 101, 102, 103); LOADF(26, 104, 105, 106, 107); LOADF(27, 108, 109, 110, 111);
  LOADF(28, 112, 113, 114, 115); LOADF(29, 116, 117, 118, 119); LOADF(30, 120, 121, 122, 123); LOADF(31, 124, 125, 126, 127);

  const int ccol = lane & 15;
  const int crow = ((lane >> 4) << 2);     // 0,4,8,12

#define SWZ(rr, cb) ((rr) * 512 + ((((cb) & ~15) ^ (((rr) & 7) << 4)) | ((cb) & 15)))

  float* hst = hstate + (size_t)(dir * 4 + bx) * 4096;
  for (int i = tid; i < 16 * 256; i += 512) {
    float v = (t0 == 0) ? 0.0f : hst[i];
    int rr = i >> 8, cc = i & 255;
    *(unsigned short*)((char*)hx + 8192 + SWZ(rr, cc * 2)) = f2bf(v);
  }
  float hreg[2][4];
#pragma unroll
  for (int j = 0; j < 2; ++j)
#pragma unroll
    for (int r = 0; r < 4; ++r) {
      int rr = crow + r, c = (w * 2 + j) * 16 + ccol;
      hreg[j][r] = (t0 == 0) ? 0.0f : hst[rr * 256 + c];
    }
  __syncthreads();

  const f32x4* XgD = Xg + (size_t)dir * (chunkT * 4) * 48 * 64;
  unsigned short* sp_bf = dir ? sbw_bf : sfw_bf;
  const int coff = dir ? 256 : 0;
  const int ardbase = (lane & 15) * 512;
  const int arxor = ((lane & 7) << 4);
  const int afc = ((lane >> 4) << 4);

  // hoisted LDS fragment-read addresses (loop-invariant; rh at +0, h at +8192)
  const int ra0 = ardbase + ((0 * 64 + afc) ^ arxor);
  const int ra1 = ardbase + ((1 * 64 + afc) ^ arxor);
  const int ra2 = ardbase + ((2 * 64 + afc) ^ arxor);
  const int ra3 = ardbase + ((3 * 64 + afc) ^ arxor);
  const int ra4 = ardbase + ((4 * 64 + afc) ^ arxor);
  const int ra5 = ardbase + ((5 * 64 + afc) ^ arxor);
  const int ra6 = ardbase + ((6 * 64 + afc) ^ arxor);
  const int ra7 = ardbase + ((7 * 64 + afc) ^ arxor);
#define HF(RA)  (*(const bf16x8*)((const char*)hx + 8192 + (RA)))
#define RHF(RA) (*(const bf16x8*)((const char*)hx + (RA)))

  // hoisted swizzled write addresses (rh at wa, h at wa+8192)
  const int cbj0 = ((w * 2 + 0) * 16 + ccol) * 2;
  const int cbj1 = ((w * 2 + 1) * 16 + ccol) * 2;
  const int wa00 = SWZ(crow + 0, cbj0), wa01 = SWZ(crow + 1, cbj0);
  const int wa02 = SWZ(crow + 2, cbj0), wa03 = SWZ(crow + 3, cbj0);
  const int wa10 = SWZ(crow + 0, cbj1), wa11 = SWZ(crow + 1, cbj1);
  const int wa12 = SWZ(crow + 2, cbj1), wa13 = SWZ(crow + 3, cbj1);

  // strided Xg pointers (pair element at +64 f32x4 = offset:1024)
  const size_t XSTEP = (size_t)4 * 48 * 64;
  const f32x4* pR = XgD + (size_t)bx * 48 * 64 + (size_t)(w * 2) * 64 + lane;
  const f32x4* pZ = pR + (size_t)32 * 64;
  const f32x4* pB = pR + (size_t)16 * 64;

  // strided output pointers
  unsigned short* pSp = sp_bf + ((size_t)(t0 * 64 + row0 + crow) * 256) + (w * 2) * 16 + ccol;
  const int g0 = (LAYER == 1 && dir) ? ((T_STEPS - 1 - t0) * 64 + row0) : (t0 * 64 + row0);
  float* pO = out ? out + ((size_t)(g0 + crow) * 512) + coff + (w * 2) * 16 + ccol : nullptr;
  float* pO2 = pO ? pO + 2 * 512 : nullptr;
  const long long OSTEP = (LAYER == 1 && dir) ? -(long long)64 * 512 : (long long)64 * 512;

  // zero quad for MFMA C-in
  f32x4 zq = {0.0f, 0.0f, 0.0f, 0.0f};

  // prologue: step-0 Xg
  f32x4 xa0 = pR[0], xa1 = pR[64], xa2 = pZ[0], xa3 = pZ[64], xb0 = pB[0], xb1 = pB[64];

#pragma unroll 1
  for (int t = t0; t < t0 + chunkT; ++t) {
    // ---------- phase A: rz = h @ Whrz, weights from pinned AGPRs ----------
    f32x4 accA0, accA1, accA2, accA3;
    {
      bf16x8 af;
      af = HF(ra0);
      MFMA_AZ(accA0, af, 0, 3, zq);   MFMA_AZ(accA1, af, 32, 35, zq);
      MFMA_AZ(accA2, af, 64, 67, zq); MFMA_AZ(accA3, af, 96, 99, zq);
      af = HF(ra1);
      MFMA_A(accA0, af, 4, 7);    MFMA_A(accA1, af, 36, 39);
      MFMA_A(accA2, af, 68, 71);  MFMA_A(accA3, af, 100, 103);
      af = HF(ra2);
      MFMA_A(accA0, af, 8, 11);   MFMA_A(accA1, af, 40, 43);
      MFMA_A(accA2, af, 72, 75);  MFMA_A(accA3, af, 104, 107);
      af = HF(ra3);
      MFMA_A(accA0, af, 12, 15);  MFMA_A(accA1, af, 44, 47);
      MFMA_A(accA2, af, 76, 79);  MFMA_A(accA3, af, 108, 111);
      af = HF(ra4);
      MFMA_A(accA0, af, 16, 19);  MFMA_A(accA1, af, 48, 51);
      MFMA_A(accA2, af, 80, 83);  MFMA_A(accA3, af, 112, 115);
      af = HF(ra5);
      MFMA_A(accA0, af, 20, 23);  MFMA_A(accA1, af, 52, 55);
      MFMA_A(accA2, af, 84, 87);  MFMA_A(accA3, af, 116, 119);
      af = HF(ra6);
      MFMA_A(accA0, af, 24, 27);  MFMA_A(accA1, af, 56, 59);
      MFMA_A(accA2, af, 88, 91);  MFMA_A(accA3, af, 120, 123);
      af = HF(ra7);
      MFMA_A(accA0, af, 28, 31);  MFMA_A(accA1, af, 60, 63);
      MFMA_A(accA2, af, 92, 95);  MFMA_A(accA3, af, 124, 127);
    }
    ACCFENCE2(accA0, accA1);

    // epilogue A (r-gates): rh -> LDS via packed bf16 pairs, hoisted addresses
    {
      float rh0[4], rh1[4];
#pragma unroll
      for (int r = 0; r < 4; ++r) {
        float v0 = accA0[r] + xa0[r];
        rh0[r] = __builtin_amdgcn_rcpf(1.0f + __builtin_amdgcn_exp2f(v0)) * hreg[0][r];
        float v1 = accA1[r] + xa1[r];
        rh1[r] = __builtin_amdgcn_rcpf(1.0f + __builtin_amdgcn_exp2f(v1)) * hreg[1][r];
      }
      unsigned a01 = cvt_pk_bf16(rh0[0], rh0[1]);
      unsigned a23 = cvt_pk_bf16(rh0[2], rh0[3]);
      unsigned b01 = cvt_pk_bf16(rh1[0], rh1[1]);
      unsigned b23 = cvt_pk_bf16(rh1[2], rh1[3]);
      *(unsigned short*)((char*)hx + wa00) = (unsigned short)a01;
      *(unsigned short*)((char*)hx + wa01) = (unsigned short)(a01 >> 16);
      *(unsigned short*)((char*)hx + wa02) = (unsigned short)a23;
      *(unsigned short*)((char*)hx + wa03) = (unsigned short)(a23 >> 16);
      *(unsigned short*)((char*)hx + wa10) = (unsigned short)b01;
      *(unsigned short*)((char*)hx + wa11) = (unsigned short)(b01 >> 16);
      *(unsigned short*)((char*)hx + wa12) = (unsigned short)b23;
      *(unsigned short*)((char*)hx + wa13) = (unsigned short)(b23 >> 16);
    }
    asm volatile("s_waitcnt lgkmcnt(0)" ::: "memory", ACLB);
    __builtin_amdgcn_s_barrier();

    // ---------- phase B ----------
    // deferred z epilogue (overlaps phase-B LDS reads)
    ACCFENCE2(accA2, accA3);
    float zreg[2][4];
#pragma unroll
    for (int r = 0; r < 4; ++r) {
      zreg[0][r] = __builtin_amdgcn_rcpf(1.0f + __builtin_amdgcn_exp2f(accA2[r] + xa2[r]));
      zreg[1][r] = __builtin_amdgcn_rcpf(1.0f + __builtin_amdgcn_exp2f(accA3[r] + xa3[r]));
    }

    // cand matmul — 4 kt-split chains, zero-quad C-in
    f32x4 accB0a, accB0b, accB1a, accB1b;
    {
      bf16x8 a;
      a = RHF(ra0);
      MFMA_VZ(accB0a, a, *(const bf16x8*)&wc_lds[((size_t)(w * 2 + 0) * 8 + 0) * 64 + lane], zq);
      MFMA_VZ(accB1a, a, *(const bf16x8*)&wc_lds[((size_t)(w * 2 + 1) * 8 + 0) * 64 + lane], zq);
      a = RHF(ra1);
      MFMA_V(accB0a, a, *(const bf16x8*)&wc_lds[((size_t)(w * 2 + 0) * 8 + 1) * 64 + lane]);
      MFMA_V(accB1a, a, *(const bf16x8*)&wc_lds[((size_t)(w * 2 + 1) * 8 + 1) * 64 + lane]);
      a = RHF(ra2);
      MFMA_V(accB0a, a, *(const bf16x8*)&wc_lds[((size_t)(w * 2 + 0) * 8 + 2) * 64 + lane]);
      MFMA_V(accB1a, a, *(const bf16x8*)&wc_lds[((size_t)(w * 2 + 1) * 8 + 2) * 64 + lane]);
      a = RHF(ra3);
      MFMA_V(accB0a, a, *(const bf16x8*)&wc_lds[((size_t)(w * 2 + 0) * 8 + 3) * 64 + lane]);
      MFMA_V(accB1a, a, *(const bf16x8*)&wc_lds[((size_t)(w * 2 + 1) * 8 + 3) * 64 + lane]);
      a = RHF(ra4);
      MFMA_VZ(accB0b, a, *(const bf16x8*)&wc_lds[((size_t)(w * 2 + 0) * 8 + 4) * 64 + lane], zq);
      MFMA_VZ(accB1b, a, *(const bf16x8*)&wc_lds[((size_t)(w * 2 + 1) * 8 + 4) * 64 + lane], zq);
      a = RHF(ra5);
      MFMA_V(accB0b, a, *(const bf16x8*)&wc_lds[((size_t)(w * 2 + 0) * 8 + 5) * 64 + lane]);
      MFMA_V(accB1b, a, *(const bf16x8*)&wc_lds[((size_t)(w * 2 + 1) * 8 + 5) * 64 + lane]);
      a = RHF(ra6);
      MFMA_V(accB0b, a, *(const bf16x8*)&wc_lds[((size_t)(w * 2 + 0) * 8 + 6) * 64 + lane]);
      MFMA_V(accB1b, a, *(const bf16x8*)&wc_lds[((size_t)(w * 2 + 1) * 8 + 6) * 64 + lane]);
      a = RHF(ra7);
      MFMA_V(accB0b, a, *(const bf16x8*)&wc_lds[((size_t)(w * 2 + 0) * 8 + 7) * 64 + lane]);
      MFMA_V(accB1b, a, *(const bf16x8*)&wc_lds[((size_t)(w * 2 + 1) * 8 + 7) * 64 + lane]);
    }
    // capture current-step cand x-parts, then prefetch next step (padded buffer)
    f32x4 cb0 = xb0, cb1 = xb1;
    pR += XSTEP; pZ += XSTEP; pB += XSTEP;
    xa0 = pR[0]; xa1 = pR[64]; xa2 = pZ[0]; xa3 = pZ[64]; xb0 = pB[0]; xb1 = pB[64];

    ACCFENCE4(accB0a, accB0b, accB1a, accB1b);
    f32x4 accB0 = accB0a + accB0b;
    f32x4 accB1 = accB1a + accB1b;

#pragma unroll
    for (int j = 0; j < 2; ++j) {
      f32x4 ac = j ? accB1 : accB0;
      f32x4 xv = j ? cb1 : cb0;
      float hn[4];
#pragma unroll
      for (int r = 0; r < 4; ++r) {
        float v = ac[r] + xv[r];
        float cand = __builtin_amdgcn_rcpf(1.0f + __builtin_amdgcn_exp2f(v)) * 2.0f - 1.0f;
        hn[r] = cand + zreg[j][r] * (hreg[j][r] - cand);
        hreg[j][r] = hn[r];
      }
      unsigned p01 = cvt_pk_bf16(hn[0], hn[1]);
      unsigned p23 = cvt_pk_bf16(hn[2], hn[3]);
      int wA = j ? wa10 : wa00, wB = j ? wa11 : wa01;
      int wC = j ? wa12 : wa02, wD = j ? wa13 : wa03;
      *(unsigned short*)((char*)hx + 8192 + wA) = (unsigned short)p01;
      *(unsigned short*)((char*)hx + 8192 + wB) = (unsigned short)(p01 >> 16);
      *(unsigned short*)((char*)hx + 8192 + wC) = (unsigned short)p23;
      *(unsigned short*)((char*)hx + 8192 + wD) = (unsigned short)(p23 >> 16);
      if (LAYER == 0) {
        pSp[(size_t)j * 16 + 0 * 256] = (unsigned short)p01;
        pSp[(size_t)j * 16 + 1 * 256] = (unsigned short)(p01 >> 16);
        pSp[(size_t)j * 16 + 2 * 256] = (unsigned short)p23;
        pSp[(size_t)j * 16 + 3 * 256] = (unsigned short)(p23 >> 16);
      } else {
        pO[(size_t)j * 16 + 0 * 512] = hn[0];
        pO[(size_t)j * 16 + 1 * 512] = hn[1];
        pO2[(size_t)j * 16 + 0 * 512] = hn[2];
        pO2[(size_t)j * 16 + 1 * 512] = hn[3];
      }
    }
    if (LAYER == 0) pSp += (size_t)64 * 256;
    else { pO += OSTEP; pO2 += OSTEP; }

    asm volatile("s_waitcnt lgkmcnt(0)" ::: "memory", ACLB);
    __builtin_amdgcn_s_barrier();
  }

  // persist h; on last chunk also write fh/bh
#pragma unroll
  for (int j = 0; j < 2; ++j)
#pragma unroll
    for (int r = 0; r < 4; ++r) {
      int rr = crow + r, c = (w * 2 + j) * 16 + ccol;
      hst[rr * 256 + c] = hreg[j][r];
      if (t0 + chunkT == T_STEPS) {
        float* dst = dout_h + (dir ? 32768 : 0) + (size_t)LAYER * 16384;
        dst[(size_t)(row0 + rr) * 256 + c] = hreg[j][r];
      }
    }
}

__global__ void diag_kernel(float* out, float v) { out[0] = v; }

// --------------------------------------------------------------------------------------
extern "C" void kernel_launch(void* const* d_in, const int* in_sizes, int n_in,
                              void* d_out, int out_size, void* d_ws, size_t ws_size,
                              hipStream_t stream) {
  const float* x     = (const float*)d_in[0];
  const float* fw_W0 = (const float*)d_in[2];
  const float* fw_b0 = (const float*)d_in[3];
  const float* fw_W1 = (const float*)d_in[4];
  const float* fw_b1 = (const float*)d_in[5];
  const float* bw_W0 = (const float*)d_in[6];
  const float* bw_b0 = (const float*)d_in[7];
  const float* bw_W1 = (const float*)d_in[8];
  const float* bw_b1 = (const float*)d_in[9];

  char* ws = (char*)d_ws;
  size_t off = 0;
  auto alloc = [&](size_t bytes) -> char* {
    char* p = ws + off; off += (bytes + 255) & ~(size_t)255; return p;
  };
  unsigned short* Wx0p  = (unsigned short*)alloc(2ull * 48 * 8 * 64 * 8 * 2);
  unsigned short* Wx1p  = (unsigned short*)alloc(2ull * 48 * 16 * 64 * 8 * 2);
  unsigned short* Whrz0 = (unsigned short*)alloc(2ull * 32 * 8 * 64 * 8 * 2);
  unsigned short* Whc0  = (unsigned short*)alloc(2ull * 16 * 8 * 64 * 8 * 2);
  unsigned short* Whrz1 = (unsigned short*)alloc(2ull * 32 * 8 * 64 * 8 * 2);
  unsigned short* Whc1  = (unsigned short*)alloc(2ull * 16 * 8 * 64 * 8 * 2);
  unsigned short* fs0   = (unsigned short*)alloc((size_t)TB * 256 * 2);
  unsigned short* bs0   = (unsigned short*)alloc((size_t)TB * 256 * 2);
  float* hstate         = (float*)alloc(2ull * 4 * 16 * 256 * 4);

  // largest chunk that fits (+1-step pad for unconditional prefetch)
  const size_t XPAD = (size_t)4 * 48 * 64 * 16;
  int chunkT = 0;
  for (int ct = 512; ct >= 8; ct >>= 1) {
    if (off + (size_t)ct * 2 * 64 * 768 * 4 + XPAD <= ws_size) { chunkT = ct; break; }
  }
  float* out = (float*)d_out;
  if (chunkT == 0) {
    diag_kernel<<<1, 1, 0, stream>>>(out, 12345.0f);
    return;
  }
  f32x4* Xg = (f32x4*)alloc((size_t)chunkT * 2 * 64 * 768 * 4 + XPAD);
  float* dout_h = out + (size_t)TB * 512;

  auto packw = [&](const float* W, int rows, int kb, int ntl, int ktl, int mode, unsigned short* dst) {
    int total = ntl * ktl * 64;
    pack_w_kernel<<<(total + 255) / 256, 256, 0, stream>>>(W, rows, kb, ntl, ktl, mode, dst);
  };
  packw(fw_W0, 512, 0,   48, 8,  0, Wx0p);
  packw(bw_W0, 512, 0,   48, 8,  0, Wx0p + 48 * 8 * 64 * 8);
  packw(fw_W1, 768, 0,   48, 16, 0, Wx1p);
  packw(bw_W1, 768, 0,   48, 16, 0, Wx1p + 48 * 16 * 64 * 8);
  packw(fw_W0, 512, 256, 32, 8,  1, Whrz0);
  packw(bw_W0, 512, 256, 32, 8,  1, Whrz0 + 32 * 8 * 64 * 8);
  packw(fw_W0, 512, 256, 16, 8,  2, Whc0);
  packw(bw_W0, 512, 256, 16, 8,  2, Whc0 + 16 * 8 * 64 * 8);
  packw(fw_W1, 768, 512, 32, 8,  1, Whrz1);
  packw(bw_W1, 768, 512, 32, 8,  1, Whrz1 + 32 * 8 * 64 * 8);
  packw(fw_W1, 768, 512, 16, 8,  2, Whc1);
  packw(bw_W1, 768, 512, 16, 8,  2, Whc1 + 16 * 8 * 64 * 8);

  dim3 rgrid(4, 2);
  // layer 0
  for (int t0 = 0; t0 < T_STEPS; t0 += chunkT) {
    dim3 ggrid(chunkT / 2, 6, 2);
    gemm_xg_kernel<0><<<ggrid, 256, 0, stream>>>(x, nullptr, nullptr, Wx0p, fw_b0, bw_b0, Xg, t0, chunkT);
    gru_kernel<0><<<rgrid, 512, 0, stream>>>(Xg,
        (const uint4*)Whrz0, (const uint4*)(Whrz0 + 32 * 8 * 64 * 8),
        (const uint4*)Whc0,  (const uint4*)(Whc0 + 16 * 8 * 64 * 8),
        fs0, bs0, nullptr, hstate, dout_h, t0, chunkT);
  }
  // layer 1
  for (int t0 = 0; t0 < T_STEPS; t0 += chunkT) {
    dim3 ggrid(chunkT / 2, 6, 2);
    gemm_xg_kernel<1><<<ggrid, 256, 0, stream>>>(nullptr, fs0, bs0, Wx1p, fw_b1, bw_b1, Xg, t0, chunkT);
    gru_kernel<1><<<rgrid, 512, 0, stream>>>(Xg,
        (const uint4*)Whrz1, (const uint4*)(Whrz1 + 32 * 8 * 64 * 8),
        (const uint4*)Whc1,  (const uint4*)(Whc1 + 16 * 8 * 64 * 8),
        nullptr, nullptr, out, hstate, dout_h, t0, chunkT);
  }
}